// Round 6
// baseline (3860.406 us; speedup 1.0000x reference)
//
#include <hip/hip_runtime.h>

typedef __attribute__((ext_vector_type(4))) float f32x4;
typedef __attribute__((ext_vector_type(8))) __bf16 bfx8;
typedef unsigned short u16;
typedef unsigned int u32;

// ---------------- helpers ----------------
__device__ __forceinline__ u16 f2bf(float f) {
  u32 u = __builtin_bit_cast(u32, f);
  u = (u + 0x7FFFu + ((u >> 16) & 1u)) >> 16;
  return (u16)u;
}
__device__ __forceinline__ float bf2f(u16 u) {
  return __builtin_bit_cast(float, ((u32)u) << 16);
}

typedef __attribute__((address_space(1))) const void gvoid;
typedef __attribute__((address_space(3))) void svoid;
__device__ __forceinline__ void gload16(const void* g, void* l) {
  __builtin_amdgcn_global_load_lds((gvoid*)g, (svoid*)l, 16, 0, 0);
}

__device__ __forceinline__ float wredsum(float v) {
#pragma unroll
  for (int o = 32; o; o >>= 1) v += __shfl_xor(v, o, 64);
  return v;
}
__device__ __forceinline__ float wredmax(float v) {
#pragma unroll
  for (int o = 32; o; o >>= 1) v = fmaxf(v, __shfl_xor(v, o, 64));
  return v;
}

// ---------------- small kernels ----------------
// fp32 [z][K][N] -> bf16 [z][N][K]
__global__ __launch_bounds__(256) void wconv_kernel(const float* __restrict__ in,
                                                    u16* __restrict__ out, int K, int N) {
  __shared__ u16 tile[32][33];
  const long z = blockIdx.z;
  const float* iz = in + z * (long)K * N;
  u16* oz = out + z * (long)K * N;
  const int n0 = blockIdx.x << 5, k0 = blockIdx.y << 5;
  const int tx = threadIdx.x & 31, ty = threadIdx.x >> 5;
#pragma unroll
  for (int i = 0; i < 4; ++i)
    tile[ty + 8 * i][tx] = f2bf(iz[(long)(k0 + ty + 8 * i) * N + n0 + tx]);
  __syncthreads();
#pragma unroll
  for (int i = 0; i < 4; ++i)
    oz[(long)(n0 + ty + 8 * i) * K + k0 + tx] = tile[tx][ty + 8 * i];
}

__global__ __launch_bounds__(256) void cvt_kernel(const float* __restrict__ in,
                                                  u16* __restrict__ out, long n) {
  long i = ((long)blockIdx.x * 256 + threadIdx.x) * 4;
  if (i + 3 < n) {
    float4 v = *(const float4*)(in + i);
    ushort4 o = {f2bf(v.x), f2bf(v.y), f2bf(v.z), f2bf(v.w)};
    *(ushort4*)(out + i) = o;
  }
}

__global__ __launch_bounds__(256) void embed_kernel(const int* __restrict__ x,
                                                    const float* __restrict__ emb,
                                                    const float* __restrict__ pe,
                                                    float* __restrict__ h,
                                                    u16* __restrict__ hb) {
  const int row = blockIdx.x;
  const int b = row >> 9, t = row & 511;
  const long tok = (long)x[b * 513 + t];
  const int d = threadIdx.x << 2;
  float4 e = *(const float4*)(emb + tok * 1024 + d);
  float4 p = *(const float4*)(pe + (long)t * 1024 + d);
  float4 v = {e.x + p.x, e.y + p.y, e.z + p.z, e.w + p.w};
  *(float4*)(h + (long)row * 1024 + d) = v;
  ushort4 o = {f2bf(v.x), f2bf(v.y), f2bf(v.z), f2bf(v.w)};
  *(ushort4*)(hb + (long)row * 1024 + d) = o;
}

// h = norm(h + delta + delta2); single-pass dual reduction
__global__ __launch_bounds__(256) void addnorm_kernel(const float* __restrict__ delta,
                                                      const float* __restrict__ delta2,
                                                      float* __restrict__ h,
                                                      u16* __restrict__ hb,
                                                      const float* __restrict__ ga,
                                                      const float* __restrict__ gb) {
  __shared__ float r1[4], r2[4];
  const long row = blockIdx.x;
  const int d = threadIdx.x << 2;
  float4 a = *(const float4*)(h + row * 1024 + d);
  float4 q = *(const float4*)(delta + row * 1024 + d);
  float4 q2 = *(const float4*)(delta2 + row * 1024 + d);
  float x0 = a.x + q.x + q2.x, x1 = a.y + q.y + q2.y;
  float x2 = a.z + q.z + q2.z, x3 = a.w + q.w + q2.w;
  float s1 = wredsum(x0 + x1 + x2 + x3);
  float s2 = wredsum(x0 * x0 + x1 * x1 + x2 * x2 + x3 * x3);
  if ((threadIdx.x & 63) == 0) { r1[threadIdx.x >> 6] = s1; r2[threadIdx.x >> 6] = s2; }
  __syncthreads();
  float S1 = r1[0] + r1[1] + r1[2] + r1[3];
  float S2 = r2[0] + r2[1] + r2[2] + r2[3];
  float mu = S1 * (1.0f / 1024.0f);
  float var = (S2 - S1 * mu) * (1.0f / 1023.0f);
  float inv = 1.0f / (sqrtf(fmaxf(var, 0.f)) + 1e-6f);
  float4 g4 = *(const float4*)(ga + d);
  float4 b4 = *(const float4*)(gb + d);
  float y0 = g4.x * (x0 - mu) * inv + b4.x;
  float y1 = g4.y * (x1 - mu) * inv + b4.y;
  float y2 = g4.z * (x2 - mu) * inv + b4.z;
  float y3 = g4.w * (x3 - mu) * inv + b4.w;
  float4 y = {y0, y1, y2, y3};
  *(float4*)(h + row * 1024 + d) = y;
  ushort4 o = {f2bf(y0), f2bf(y1), f2bf(y2), f2bf(y3)};
  *(ushort4*)(hb + row * 1024 + d) = o;
}

// in-place log_softmax over rows of 32000 fp32 (fallback)
__global__ __launch_bounds__(256) void logsoftmax_kernel(float* __restrict__ lg) {
  const long row = blockIdx.x;
  float* lr = lg + row * 32000L;
  float m = -1e30f, s = 0.f;
  for (int j = threadIdx.x; j < 8000; j += 256) {
    float4 v = *(const float4*)(lr + (long)j * 4);
    float lm = fmaxf(fmaxf(v.x, v.y), fmaxf(v.z, v.w));
    if (lm > m) { s *= __expf(m - lm); m = lm; }
    s += __expf(v.x - m) + __expf(v.y - m) + __expf(v.z - m) + __expf(v.w - m);
  }
#pragma unroll
  for (int o = 32; o; o >>= 1) {
    float om = __shfl_xor(m, o, 64), os = __shfl_xor(s, o, 64);
    float M = fmaxf(m, om);
    s = s * __expf(m - M) + os * __expf(om - M);
    m = M;
  }
  __shared__ float rm[4], rs[4];
  if ((threadIdx.x & 63) == 0) { rm[threadIdx.x >> 6] = m; rs[threadIdx.x >> 6] = s; }
  __syncthreads();
  float M = fmaxf(fmaxf(rm[0], rm[1]), fmaxf(rm[2], rm[3]));
  float S = rs[0] * __expf(rm[0] - M) + rs[1] * __expf(rm[1] - M) +
            rs[2] * __expf(rm[2] - M) + rs[3] * __expf(rm[3] - M);
  float lse = M + __logf(S);
  for (int j = threadIdx.x; j < 8000; j += 256) {
    float4 v = *(const float4*)(lr + (long)j * 4);
    v.x -= lse; v.y -= lse; v.z -= lse; v.w -= lse;
    *(float4*)(lr + (long)j * 4) = v;
  }
}

// LDS-cached log_softmax from bf16 logits -> f32 out.
__global__ __launch_bounds__(512) void logsoftmax_bf16_kernel(const u16* __restrict__ lg,
                                                              float* __restrict__ out) {
  __shared__ u16 rl[32000];
  __shared__ float rr[8];
  const long row = blockIdx.x;
  const u16* lr = lg + row * 32000L;
  float* od = out + row * 32000L;
  const int tid = threadIdx.x;
  float m0 = -1e30f, m1 = -1e30f;
  for (int j = tid * 8; j < 32000; j += 4096) {
    ushort4 a = *(const ushort4*)(lr + j);
    ushort4 b = *(const ushort4*)(lr + j + 4);
    *(ushort4*)&rl[j] = a;
    *(ushort4*)&rl[j + 4] = b;
    m0 = fmaxf(m0, fmaxf(fmaxf(bf2f(a.x), bf2f(a.y)), fmaxf(bf2f(a.z), bf2f(a.w))));
    m1 = fmaxf(m1, fmaxf(fmaxf(bf2f(b.x), bf2f(b.y)), fmaxf(bf2f(b.z), bf2f(b.w))));
  }
  float m = wredmax(fmaxf(m0, m1));
  if ((tid & 63) == 0) rr[tid >> 6] = m;
  __syncthreads();
  m = fmaxf(fmaxf(fmaxf(rr[0], rr[1]), fmaxf(rr[2], rr[3])),
            fmaxf(fmaxf(rr[4], rr[5]), fmaxf(rr[6], rr[7])));
  __syncthreads();
  float s0 = 0.f, s1 = 0.f;
  for (int j = tid * 8; j < 32000; j += 4096) {
    ushort4 a = *(const ushort4*)&rl[j];
    ushort4 b = *(const ushort4*)&rl[j + 4];
    s0 += __expf(bf2f(a.x) - m) + __expf(bf2f(a.y) - m) +
          __expf(bf2f(a.z) - m) + __expf(bf2f(a.w) - m);
    s1 += __expf(bf2f(b.x) - m) + __expf(bf2f(b.y) - m) +
          __expf(bf2f(b.z) - m) + __expf(bf2f(b.w) - m);
  }
  float s = wredsum(s0 + s1);
  if ((tid & 63) == 0) rr[tid >> 6] = s;
  __syncthreads();
  s = rr[0] + rr[1] + rr[2] + rr[3] + rr[4] + rr[5] + rr[6] + rr[7];
  const float lse = m + __logf(s);
  for (int j = tid * 8; j < 32000; j += 4096) {
    ushort4 a = *(const ushort4*)&rl[j];
    ushort4 b = *(const ushort4*)&rl[j + 4];
    float4 o0 = {bf2f(a.x) - lse, bf2f(a.y) - lse, bf2f(a.z) - lse, bf2f(a.w) - lse};
    float4 o1 = {bf2f(b.x) - lse, bf2f(b.y) - lse, bf2f(b.z) - lse, bf2f(b.w) - lse};
    *(float4*)(od + j) = o0;
    *(float4*)(od + j + 4) = o1;
  }
}

// ---------------- fused flash attention (barrier-free) ----------------
// K/V per (b,h) is 64-256 KB -> L1/L2-resident; all 4 waves read identical
// fragments (L1 broadcast). No K/V LDS staging, no __syncthreads: waves fully
// independent; per-wave P-bounce LDS only. Zero-threshold defer-max (exact).
template <int SKV>
__global__ __launch_bounds__(256) void attn_kernel(const u16* __restrict__ Q,
                                                   const u16* __restrict__ Kb,
                                                   const u16* __restrict__ Vt,
                                                   u16* __restrict__ ctx) {
  __shared__ u16 Pl[4][16][72];  // per-wave P: [q][kv]
  const int tid = threadIdx.x, lane = tid & 63, wave = tid >> 6;
  const int l15 = lane & 15, lg = lane >> 4;
  const int bh = blockIdx.y;
  const int qrow = blockIdx.x * 64 + wave * 16 + l15;
  const u16* qp = Q + ((long)bh * 512 + qrow) * 64 + lg * 8;
  bfx8 qf0 = *(const bfx8*)(qp);
  bfx8 qf1 = *(const bfx8*)(qp + 32);
  const u16* Kbh = Kb + (long)bh * SKV * 64;
  const u16* Vbh = Vt + (long)bh * 64 * SKV;

  const f32x4 zf = {0.f, 0.f, 0.f, 0.f};
  f32x4 acc_o[4] = {zf, zf, zf, zf};
  float mrun = -1e30f, lrun = 0.f;

#pragma unroll 1
  for (int kv0 = 0; kv0 < SKV; kv0 += 64) {
    // S^T tile: lane holds S[q=l15][kv=kvt*16+lg*4+r], K-frags straight from L1/L2
    f32x4 sacc[4];
#pragma unroll
    for (int kvt = 0; kvt < 4; ++kvt) {
      const u16* kr = Kbh + (long)(kv0 + kvt * 16 + l15) * 64 + lg * 8;
      bfx8 kf0 = *(const bfx8*)kr;
      bfx8 kf1 = *(const bfx8*)(kr + 32);
      f32x4 t = __builtin_amdgcn_mfma_f32_16x16x32_bf16(kf0, qf0, zf, 0, 0, 0);
      sacc[kvt] = __builtin_amdgcn_mfma_f32_16x16x32_bf16(kf1, qf1, t, 0, 0, 0);
    }
    // online softmax (q = l15; reduce over lg groups)
    float pm = -1e30f;
#pragma unroll
    for (int kvt = 0; kvt < 4; ++kvt)
#pragma unroll
      for (int r = 0; r < 4; ++r) pm = fmaxf(pm, sacc[kvt][r]);
    pm = fmaxf(pm, __shfl_xor(pm, 16, 64));
    pm = fmaxf(pm, __shfl_xor(pm, 32, 64));
    pm *= 0.125f;
    const bool grow = !__all(pm <= mrun);  // exact defer: skip rescale if max unchanged
    const float mnew = grow ? fmaxf(mrun, pm) : mrun;
    float psum = 0.f;
#pragma unroll
    for (int kvt = 0; kvt < 4; ++kvt)
#pragma unroll
      for (int r = 0; r < 4; ++r) {
        float p = __expf(sacc[kvt][r] * 0.125f - mnew);
        psum += p;
        Pl[wave][l15][kvt * 16 + lg * 4 + r] = f2bf(p);
      }
    psum += __shfl_xor(psum, 16, 64);
    psum += __shfl_xor(psum, 32, 64);
    if (grow) {
      const float corr = __expf(mrun - mnew);
      lrun = lrun * corr + psum;
      mrun = mnew;
#pragma unroll
      for (int dt = 0; dt < 4; ++dt) {
        acc_o[dt][0] *= corr; acc_o[dt][1] *= corr;
        acc_o[dt][2] *= corr; acc_o[dt][3] *= corr;
      }
    } else {
      lrun += psum;
    }
    // O^T += V^T-frag x P-frag (V-frags from L1/L2; P via wave-local LDS)
    bfx8 pf0 = *(const bfx8*)&Pl[wave][l15][lg * 8];
    bfx8 pf1 = *(const bfx8*)&Pl[wave][l15][32 + lg * 8];
#pragma unroll
    for (int dt = 0; dt < 4; ++dt) {
      const u16* vr = Vbh + (long)(dt * 16 + l15) * SKV + kv0 + lg * 8;
      bfx8 vf0 = *(const bfx8*)vr;
      bfx8 vf1 = *(const bfx8*)(vr + 32);
      acc_o[dt] = __builtin_amdgcn_mfma_f32_16x16x32_bf16(vf0, pf0, acc_o[dt], 0, 0, 0);
      acc_o[dt] = __builtin_amdgcn_mfma_f32_16x16x32_bf16(vf1, pf1, acc_o[dt], 0, 0, 0);
    }
  }
  const float inv = 1.0f / lrun;
  const int b = bh >> 4, hh = bh & 15;
  u16* crow = ctx + ((long)b * 512 + qrow) * 1024 + hh * 64;
#pragma unroll
  for (int dt = 0; dt < 4; ++dt)
#pragma unroll
    for (int r = 0; r < 4; ++r)
      crow[dt * 16 + lg * 4 + r] = f2bf(acc_o[dt][r] * inv);
}

// ---------------- 128x128 GEMM (2-barrier, m97 structure) ----------------
// z = K-split index; bias only for z==0. EPI: 0=f32 rm, 1=bf16 rm, 3=bf16 [b,h,t,dk]
template <int BM, int BN, int WMW, int WNW, int EPI, bool RELU>
__global__ __launch_bounds__(256) void gemm_bt(const u16* __restrict__ A, long sAz, int lda,
                                               const u16* __restrict__ Bt, long sBz, int ldb,
                                               const float* __restrict__ bias,
                                               void* __restrict__ out, long sCz, int ldc,
                                               int K, int Ttok) {
  constexpr int WROWS = BM / WMW, WCOLS = BN / WNW;
  constexpr int MI = WROWS / 16, NI = WCOLS / 16;
  __shared__ u16 As[BM * 32];
  __shared__ u16 Bs[BN * 32];
  const int tid = threadIdx.x, lane = tid & 63, wave = tid >> 6;
  const int l15 = lane & 15, lg = lane >> 4;
  const int wm = wave / WNW, wn = wave % WNW;
  const int bx = blockIdx.x, by = blockIdx.y;
  const long z = blockIdx.z;
  const int srow = tid >> 2, scol = (tid & 3) << 3;
  const u16* Aa = A + z * sAz + (long)(by * BM + srow) * lda + scol;
  const u16* Ba = Bt + z * sBz + (long)(bx * BN + srow) * ldb + scol;

  f32x4 acc[MI][NI];
#pragma unroll
  for (int i = 0; i < MI; ++i)
#pragma unroll
    for (int j = 0; j < NI; ++j) acc[i][j] = (f32x4){0.f, 0.f, 0.f, 0.f};

  for (int kt = 0; kt < K; kt += 32) {
#pragma unroll
    for (int i = 0; i < BM / 64; ++i)
      gload16(Aa + (long)i * 64 * lda + kt, &As[i * 2048 + tid * 8]);
#pragma unroll
    for (int i = 0; i < BN / 64; ++i)
      gload16(Ba + (long)i * 64 * ldb + kt, &Bs[i * 2048 + tid * 8]);
    __syncthreads();
    bfx8 afr[MI], bfr[NI];
#pragma unroll
    for (int i = 0; i < MI; ++i)
      afr[i] = *(const bfx8*)&As[(wm * WROWS + i * 16 + l15) * 32 + (lg << 3)];
#pragma unroll
    for (int j = 0; j < NI; ++j)
      bfr[j] = *(const bfx8*)&Bs[(wn * WCOLS + j * 16 + l15) * 32 + (lg << 3)];
#pragma unroll
    for (int i = 0; i < MI; ++i)
#pragma unroll
      for (int j = 0; j < NI; ++j)
        acc[i][j] = __builtin_amdgcn_mfma_f32_16x16x32_bf16(afr[i], bfr[j], acc[i][j], 0, 0, 0);
    __syncthreads();
  }

  const int gm0 = by * BM + wm * WROWS;
  const int gn0 = bx * BN + wn * WCOLS;
#pragma unroll
  for (int i = 0; i < MI; ++i) {
#pragma unroll
    for (int j = 0; j < NI; ++j) {
      const int gn = gn0 + j * 16 + l15;
      const float bv = (bias && z == 0) ? bias[gn] : 0.f;
#pragma unroll
      for (int r = 0; r < 4; ++r) {
        const int gm = gm0 + i * 16 + (lg << 2) + r;
        float v = acc[i][j][r] + bv;
        if (RELU) v = fmaxf(v, 0.f);
        if constexpr (EPI == 0) {
          ((float*)out)[z * sCz + (long)gm * ldc + gn] = v;
        } else if constexpr (EPI == 1) {
          ((u16*)out)[z * sCz + (long)gm * ldc + gn] = f2bf(v);
        } else if constexpr (EPI == 3) {
          const int b = gm / Ttok, t = gm - b * Ttok;
          const int hh = gn >> 6, dk = gn & 63;
          ((u16*)out)[(((long)(b * 16 + hh) * Ttok + t) << 6) + dk] = f2bf(v);
        }
      }
    }
  }
}

// ---------------- 256x256 8-phase GEMM (T2+T3+T4+T5) ----------------
// Plain mt-inner linear order: the gx mt-blocks of one nt-column dispatch
// near-simultaneously -> each B panel fetched from HBM once (write-stream
// L3 eviction harmless since panels are never revisited).
#define MMAQ(hm, hn)                                                                   \
  {                                                                                    \
    _Pragma("unroll") for (int kk = 0; kk < 2; ++kk)                                   \
        _Pragma("unroll") for (int i = 0; i < 4; ++i)                                  \
            _Pragma("unroll") for (int jn = 0; jn < 2; ++jn)                           \
                acc[(hm)*4 + i][(hn)*2 + jn] = __builtin_amdgcn_mfma_f32_16x16x32_bf16( \
                    a[i][kk], b[jn][kk], acc[(hm)*4 + i][(hn)*2 + jn], 0, 0, 0);       \
  }

template <int EPI, bool RELU>
__global__ __launch_bounds__(512, 2) void gemm256(const u16* __restrict__ A, int lda,
                                                  const u16* __restrict__ Bt, int ldb,
                                                  const float* __restrict__ bias,
                                                  void* __restrict__ out, int ldc, int K,
                                                  int Ttok, void* __restrict__ out2,
                                                  void* __restrict__ out3, int gx) {
  __shared__ u16 lds[2][2][2][8192];  // [dbuf][A/B][half][128*64]
  const int tid = threadIdx.x, lane = tid & 63;
  const int wid = tid >> 6, wm = wid >> 2, wn = wid & 3;
  const int l15 = lane & 15, lg = lane >> 4;
  const int mt = blockIdx.x % gx;
  const int nt_ = blockIdx.x / gx;
  const int NT = K >> 6;

  const int r0 = tid >> 3;
  const int blkx = (tid & 7) ^ (r0 & 7);
  const u16* Abase = A + (long)(mt * 256 + r0) * lda + blkx * 8;
  const u16* Bbase = Bt + (long)(nt_ * 256 + r0) * ldb + blkx * 8;

  auto stageA = [&](int s, int half) {
    const int kts = (s < NT ? s : NT - 1) << 6;
    const u16* g = Abase + (long)(half * 128) * lda + kts;
    gload16(g, &lds[s & 1][0][half][tid * 8]);
    gload16(g + (long)64 * lda, &lds[s & 1][0][half][(512 + tid) * 8]);
  };
  auto stageB = [&](int s, int half) {
    const int kts = (s < NT ? s : NT - 1) << 6;
    const u16* g = Bbase + (long)(half * 128) * ldb + kts;
    gload16(g, &lds[s & 1][1][half][tid * 8]);
    gload16(g + (long)64 * ldb, &lds[s & 1][1][half][(512 + tid) * 8]);
  };

  f32x4 acc[8][4];
#pragma unroll
  for (int i = 0; i < 8; ++i)
#pragma unroll
    for (int j = 0; j < 4; ++j) acc[i][j] = (f32x4){0.f, 0.f, 0.f, 0.f};
  bfx8 a[4][2], b[2][2];

  const int sw = l15 & 7;
  auto loadA = [&](int buf, int hm) {
#pragma unroll
    for (int i = 0; i < 4; ++i) {
      const int row = hm * 64 + i * 16 + l15;
#pragma unroll
      for (int kk = 0; kk < 2; ++kk)
        a[i][kk] = *(const bfx8*)&lds[buf][0][wm][row * 64 + (((kk * 4 + lg) ^ sw) << 3)];
    }
  };
  auto loadB = [&](int buf, int hn) {
#pragma unroll
    for (int jn = 0; jn < 2; ++jn) {
      const int row = (wn & 1) * 64 + hn * 32 + jn * 16 + l15;
#pragma unroll
      for (int kk = 0; kk < 2; ++kk)
        b[jn][kk] = *(const bfx8*)&lds[buf][1][wn >> 1][row * 64 + (((kk * 4 + lg) ^ sw) << 3)];
    }
  };

  stageA(0, 0); stageA(0, 1); stageB(0, 0); stageB(0, 1);
  stageA(1, 0); stageA(1, 1);
  asm volatile("s_waitcnt vmcnt(4)" ::: "memory");
  __builtin_amdgcn_s_barrier();

  for (int t = 0; t < NT; ++t) {
    const int p = t & 1;
    loadA(p, 0); loadB(p, 0);
    stageB(t + 1, 0);
    __builtin_amdgcn_s_barrier();
    asm volatile("s_waitcnt lgkmcnt(0)" ::: "memory");
    __builtin_amdgcn_s_setprio(1);
    MMAQ(0, 0);
    __builtin_amdgcn_s_setprio(0);
    __builtin_amdgcn_s_barrier();
    loadB(p, 1);
    stageB(t + 1, 1);
    __builtin_amdgcn_s_barrier();
    asm volatile("s_waitcnt lgkmcnt(0)" ::: "memory");
    __builtin_amdgcn_s_setprio(1);
    MMAQ(0, 1);
    __builtin_amdgcn_s_setprio(0);
    __builtin_amdgcn_s_barrier();
    loadA(p, 1); loadB(p, 0);
    stageA(t + 2, 0);
    __builtin_amdgcn_s_barrier();
    asm volatile("s_waitcnt lgkmcnt(0)" ::: "memory");
    __builtin_amdgcn_s_setprio(1);
    MMAQ(1, 0);
    __builtin_amdgcn_s_setprio(0);
    __builtin_amdgcn_s_barrier();
    loadB(p, 1);
    stageA(t + 2, 1);
    asm volatile("s_waitcnt vmcnt(4)" ::: "memory");
    __builtin_amdgcn_s_barrier();
    asm volatile("s_waitcnt lgkmcnt(0)" ::: "memory");
    __builtin_amdgcn_s_setprio(1);
    MMAQ(1, 1);
    __builtin_amdgcn_s_setprio(0);
    __builtin_amdgcn_s_barrier();
  }

  const int gm0 = mt * 256 + wm * 128;
  const int gn0 = nt_ * 256 + wn * 64;
#pragma unroll
  for (int ii = 0; ii < 8; ++ii) {
#pragma unroll
    for (int jj = 0; jj < 4; ++jj) {
      const int gn = gn0 + jj * 16 + l15;
      const float bv = bias ? bias[gn] : 0.f;
#pragma unroll
      for (int r = 0; r < 4; ++r) {
        const int gm = gm0 + ii * 16 + (lg << 2) + r;
        float v = acc[ii][jj][r] + bv;
        if (RELU) v = fmaxf(v, 0.f);
        if constexpr (EPI == 0) {
          ((float*)out)[(long)gm * ldc + gn] = v;
        } else if constexpr (EPI == 1) {
          ((u16*)out)[(long)gm * ldc + gn] = f2bf(v);
        } else if constexpr (EPI == 6) {
          const int bq = gm / Ttok, t2 = gm - bq * Ttok;
          const int sec = gn >> 10, w1 = gn & 1023;
          const int hh = w1 >> 6, dk = w1 & 63;
          const u16 val = f2bf(v);
          if (sec == 0)
            ((u16*)out)[(((long)(bq * 16 + hh) * Ttok + t2) << 6) + dk] = val;
          else if (sec == 1)
            ((u16*)out2)[(((long)(bq * 16 + hh) * Ttok + t2) << 6) + dk] = val;
          else
            ((u16*)out3)[((long)((bq * 16 + hh) << 6) + dk) * Ttok + t2] = val;
        } else if constexpr (EPI == 7) {
          const int bq = gm / Ttok, t2 = gm - bq * Ttok;
          const int sec = gn >> 10, w1 = gn & 1023;
          const int hh = w1 >> 6, dk = w1 & 63;
          const u16 val = f2bf(v);
          if (sec == 0)
            ((u16*)out)[(((long)(bq * 16 + hh) * Ttok + t2) << 6) + dk] = val;
          else
            ((u16*)out2)[((long)((bq * 16 + hh) << 6) + dk) * Ttok + t2] = val;
        }
      }
    }
  }
}

// ---------------- driver ----------------
extern "C" void kernel_launch(void* const* d_in, const int* in_sizes, int n_in,
                              void* d_out, int out_size, void* d_ws, size_t ws_size,
                              hipStream_t stream) {
  const int* x = (const int*)d_in[0];
  const float* enc = (const float*)d_in[1];
  const float* emb = (const float*)d_in[2];
  const float* pe = (const float*)d_in[3];
  const float* a1w = (const float*)d_in[4];
  const float* a1b = (const float*)d_in[5];
  const float* a2w = (const float*)d_in[6];
  const float* a2b = (const float*)d_in[7];
  const float* nra = (const float*)d_in[8];
  const float* nrb = (const float*)d_in[9];
  const float* f1w = (const float*)d_in[10];
  const float* f1b = (const float*)d_in[11];
  const float* f2w = (const float*)d_in[12];
  const float* f2b = (const float*)d_in[13];
  const float* fcw = (const float*)d_in[14];
  const float* fcb = (const float*)d_in[15];
  float* out = (float*)d_out;

  char* base = (char*)d_ws;
  size_t off = 0;
  auto alloc = [&](size_t bytes) -> void* {
    void* p = base + off;
    off += (bytes + 255) & ~(size_t)255;
    return p;
  };
  const long wsz = 1024 * 1024;
  const bool big = ws_size >= (600ull << 20);
  u16* wT = (u16*)alloc(96ull * wsz * 2);    // all transposed weights: a1|a2|f1|f2
  u16* encb = (u16*)alloc(8ull * wsz * 2);   // encoder bf16 [8192,1024]
  float* h = (float*)alloc(4ull * wsz * 4);  // residual f32 [4096,1024]
  u16* hb = (u16*)alloc(4ull * wsz * 2);     // bf16 copy of h
  u16* qb = (u16*)alloc(4ull * wsz * 2);     // [B,H,512,64]
  u16* kb = (u16*)alloc(8ull * wsz * 2);     // [B,H,<=1024,64]
  u16* vtb = (u16*)alloc(8ull * wsz * 2);    // [B,H,64,<=1024]
  u16* ctxb = (u16*)alloc(4ull * wsz * 2);   // [4096,1024] bf16
  float* af = (float*)alloc(4ull * wsz * 4); // K-split partial 0
  float* af2 = (float*)alloc(4ull * wsz * 4);// K-split partial 1
  u16* midb = (u16*)alloc(16ull * wsz * 2);  // FFN mid bf16 [4096,4096]
  u16* fcT = qb;                             // fc^T (64 MB) aliases qb.. after layers
  u16* lgb = big ? (u16*)alloc(4096ull * 32000 * 2) : nullptr;  // bf16 logits

  u16* wTa1 = wT;               // [L][4][1024][1024]^T
  u16* wTa2 = wT + 24 * wsz;
  u16* wTf1 = wT + 48 * wsz;    // [L][4096][1024]
  u16* wTf2 = wT + 72 * wsz;    // [L][1024][4096]

  cvt_kernel<<<dim3(8192), dim3(256), 0, stream>>>(enc, encb, 8ll * wsz);
  embed_kernel<<<dim3(4096), dim3(256), 0, stream>>>(x, emb, pe, h, hb);
  wconv_kernel<<<dim3(32, 32, 24), dim3(256), 0, stream>>>(a1w, wTa1, 1024, 1024);
  wconv_kernel<<<dim3(32, 32, 24), dim3(256), 0, stream>>>(a2w, wTa2, 1024, 1024);
  wconv_kernel<<<dim3(128, 32, 6), dim3(256), 0, stream>>>(f1w, wTf1, 1024, 4096);
  wconv_kernel<<<dim3(32, 128, 6), dim3(256), 0, stream>>>(f2w, wTf2, 4096, 1024);

  for (int l = 0; l < 6; ++l) {
    const float* b1 = a1b + (long)l * 4096;
    const float* b2 = a2b + (long)l * 4096;
    const u16* w1 = wTa1 + (long)l * 4 * wsz;
    const u16* w2 = wTa2 + (long)l * 4 * wsz;

    // ---- self attention ----
    gemm256<6, false><<<dim3(192), dim3(512), 0, stream>>>(
        hb, 1024, w1, 1024, b1, qb, 0, 1024, 512, kb, vtb, 16);
    attn_kernel<512><<<dim3(8, 128), dim3(256), 0, stream>>>(qb, kb, vtb, ctxb);
    gemm_bt<128, 128, 2, 2, 0, false><<<dim3(8, 32, 2), dim3(256), 0, stream>>>(
        ctxb, 512, 1024, w1 + 3 * wsz, 512, 1024, b1 + 3072, af, 4194304, 1024, 512, 0);
    addnorm_kernel<<<dim3(4096), dim3(256), 0, stream>>>(
        af, af2, h, hb, nra + (l * 3 + 0) * 1024, nrb + (l * 3 + 0) * 1024);

    // ---- cross attention ----
    gemm_bt<128, 128, 2, 2, 3, false><<<dim3(8, 32, 1), dim3(256), 0, stream>>>(
        hb, 0, 1024, w2, 0, 1024, b2, qb, 0, 0, 1024, 512);
    gemm256<7, false><<<dim3(256), dim3(512), 0, stream>>>(
        encb, 1024, w2 + wsz, 1024, b2 + 1024, kb, 0, 1024, 1024, vtb, nullptr, 32);
    attn_kernel<1024><<<dim3(8, 128), dim3(256), 0, stream>>>(qb, kb, vtb, ctxb);
    gemm_bt<128, 128, 2, 2, 0, false><<<dim3(8, 32, 2), dim3(256), 0, stream>>>(
        ctxb, 512, 1024, w2 + 3 * wsz, 512, 1024, b2 + 3072, af, 4194304, 1024, 512, 0);
    addnorm_kernel<<<dim3(4096), dim3(256), 0, stream>>>(
        af, af2, h, hb, nra + (l * 3 + 1) * 1024, nrb + (l * 3 + 1) * 1024);

    // ---- ffn ----
    gemm256<1, true><<<dim3(256), dim3(512), 0, stream>>>(
        hb, 1024, wTf1 + (long)l * 4 * wsz, 1024, f1b + (long)l * 4096, midb, 4096, 1024, 0,
        nullptr, nullptr, 16);
    gemm_bt<128, 128, 2, 2, 0, false><<<dim3(8, 32, 2), dim3(256), 0, stream>>>(
        midb, 2048, 4096, wTf2 + (long)l * 4 * wsz, 2048, 4096, f2b + (long)l * 1024, af,
        4194304, 1024, 2048, 0);
    addnorm_kernel<<<dim3(4096), dim3(256), 0, stream>>>(
        af, af2, h, hb, nra + (l * 3 + 2) * 1024, nrb + (l * 3 + 2) * 1024);
  }

  // final projection + log_softmax
  wconv_kernel<<<dim3(1000, 32, 1), dim3(256), 0, stream>>>(fcw, fcT, 1024, 32000);
  if (big) {
    gemm256<1, false><<<dim3(2000), dim3(512), 0, stream>>>(
        hb, 1024, fcT, 1024, fcb, lgb, 32000, 1024, 0, nullptr, nullptr, 16);
    logsoftmax_bf16_kernel<<<dim3(4096), dim3(512), 0, stream>>>(lgb, out);
  } else {
    gemm256<0, false><<<dim3(2000), dim3(512), 0, stream>>>(
        hb, 1024, fcT, 1024, fcb, out, 32000, 1024, 0, nullptr, nullptr, 16);
    logsoftmax_kernel<<<dim3(4096), dim3(256), 0, stream>>>(out);
  }
}

// Round 8
// 3414.211 us; speedup vs baseline: 1.1307x; 1.1307x over previous
//
#include <hip/hip_runtime.h>

typedef __attribute__((ext_vector_type(4))) float f32x4;
typedef __attribute__((ext_vector_type(8))) __bf16 bfx8;
typedef unsigned short u16;
typedef unsigned int u32;

// ---------------- helpers ----------------
__device__ __forceinline__ u16 f2bf(float f) {
  u32 u = __builtin_bit_cast(u32, f);
  u = (u + 0x7FFFu + ((u >> 16) & 1u)) >> 16;
  return (u16)u;
}
__device__ __forceinline__ float bf2f(u16 u) {
  return __builtin_bit_cast(float, ((u32)u) << 16);
}

typedef __attribute__((address_space(1))) const void gvoid;
typedef __attribute__((address_space(3))) void svoid;
__device__ __forceinline__ void gload16(const void* g, void* l) {
  __builtin_amdgcn_global_load_lds((gvoid*)g, (svoid*)l, 16, 0, 0);
}

__device__ __forceinline__ float wredsum(float v) {
#pragma unroll
  for (int o = 32; o; o >>= 1) v += __shfl_xor(v, o, 64);
  return v;
}
__device__ __forceinline__ float wredmax(float v) {
#pragma unroll
  for (int o = 32; o; o >>= 1) v = fmaxf(v, __shfl_xor(v, o, 64));
  return v;
}

// ---------------- small kernels ----------------
// fp32 [z][K][N] -> bf16 [z][N][K]
__global__ __launch_bounds__(256) void wconv_kernel(const float* __restrict__ in,
                                                    u16* __restrict__ out, int K, int N) {
  __shared__ u16 tile[32][33];
  const long z = blockIdx.z;
  const float* iz = in + z * (long)K * N;
  u16* oz = out + z * (long)K * N;
  const int n0 = blockIdx.x << 5, k0 = blockIdx.y << 5;
  const int tx = threadIdx.x & 31, ty = threadIdx.x >> 5;
#pragma unroll
  for (int i = 0; i < 4; ++i)
    tile[ty + 8 * i][tx] = f2bf(iz[(long)(k0 + ty + 8 * i) * N + n0 + tx]);
  __syncthreads();
#pragma unroll
  for (int i = 0; i < 4; ++i)
    oz[(long)(n0 + ty + 8 * i) * K + k0 + tx] = tile[tx][ty + 8 * i];
}

__global__ __launch_bounds__(256) void cvt_kernel(const float* __restrict__ in,
                                                  u16* __restrict__ out, long n) {
  long i = ((long)blockIdx.x * 256 + threadIdx.x) * 4;
  if (i + 3 < n) {
    float4 v = *(const float4*)(in + i);
    ushort4 o = {f2bf(v.x), f2bf(v.y), f2bf(v.z), f2bf(v.w)};
    *(ushort4*)(out + i) = o;
  }
}

__global__ __launch_bounds__(256) void embed_kernel(const int* __restrict__ x,
                                                    const float* __restrict__ emb,
                                                    const float* __restrict__ pe,
                                                    float* __restrict__ h,
                                                    u16* __restrict__ hb) {
  const int row = blockIdx.x;
  const int b = row >> 9, t = row & 511;
  const long tok = (long)x[b * 513 + t];
  const int d = threadIdx.x << 2;
  float4 e = *(const float4*)(emb + tok * 1024 + d);
  float4 p = *(const float4*)(pe + (long)t * 1024 + d);
  float4 v = {e.x + p.x, e.y + p.y, e.z + p.z, e.w + p.w};
  *(float4*)(h + (long)row * 1024 + d) = v;
  ushort4 o = {f2bf(v.x), f2bf(v.y), f2bf(v.z), f2bf(v.w)};
  *(ushort4*)(hb + (long)row * 1024 + d) = o;
}

// h = norm(h + delta + delta2); single-pass dual reduction
__global__ __launch_bounds__(256) void addnorm_kernel(const float* __restrict__ delta,
                                                      const float* __restrict__ delta2,
                                                      float* __restrict__ h,
                                                      u16* __restrict__ hb,
                                                      const float* __restrict__ ga,
                                                      const float* __restrict__ gb) {
  __shared__ float r1[4], r2[4];
  const long row = blockIdx.x;
  const int d = threadIdx.x << 2;
  float4 a = *(const float4*)(h + row * 1024 + d);
  float4 q = *(const float4*)(delta + row * 1024 + d);
  float4 q2 = *(const float4*)(delta2 + row * 1024 + d);
  float x0 = a.x + q.x + q2.x, x1 = a.y + q.y + q2.y;
  float x2 = a.z + q.z + q2.z, x3 = a.w + q.w + q2.w;
  float s1 = wredsum(x0 + x1 + x2 + x3);
  float s2 = wredsum(x0 * x0 + x1 * x1 + x2 * x2 + x3 * x3);
  if ((threadIdx.x & 63) == 0) { r1[threadIdx.x >> 6] = s1; r2[threadIdx.x >> 6] = s2; }
  __syncthreads();
  float S1 = r1[0] + r1[1] + r1[2] + r1[3];
  float S2 = r2[0] + r2[1] + r2[2] + r2[3];
  float mu = S1 * (1.0f / 1024.0f);
  float var = (S2 - S1 * mu) * (1.0f / 1023.0f);
  float inv = 1.0f / (sqrtf(fmaxf(var, 0.f)) + 1e-6f);
  float4 g4 = *(const float4*)(ga + d);
  float4 b4 = *(const float4*)(gb + d);
  float y0 = g4.x * (x0 - mu) * inv + b4.x;
  float y1 = g4.y * (x1 - mu) * inv + b4.y;
  float y2 = g4.z * (x2 - mu) * inv + b4.z;
  float y3 = g4.w * (x3 - mu) * inv + b4.w;
  float4 y = {y0, y1, y2, y3};
  *(float4*)(h + row * 1024 + d) = y;
  ushort4 o = {f2bf(y0), f2bf(y1), f2bf(y2), f2bf(y3)};
  *(ushort4*)(hb + row * 1024 + d) = o;
}

// in-place log_softmax over rows of 32000 fp32 (fallback)
__global__ __launch_bounds__(256) void logsoftmax_kernel(float* __restrict__ lg) {
  const long row = blockIdx.x;
  float* lr = lg + row * 32000L;
  float m = -1e30f, s = 0.f;
  for (int j = threadIdx.x; j < 8000; j += 256) {
    float4 v = *(const float4*)(lr + (long)j * 4);
    float lm = fmaxf(fmaxf(v.x, v.y), fmaxf(v.z, v.w));
    if (lm > m) { s *= __expf(m - lm); m = lm; }
    s += __expf(v.x - m) + __expf(v.y - m) + __expf(v.z - m) + __expf(v.w - m);
  }
#pragma unroll
  for (int o = 32; o; o >>= 1) {
    float om = __shfl_xor(m, o, 64), os = __shfl_xor(s, o, 64);
    float M = fmaxf(m, om);
    s = s * __expf(m - M) + os * __expf(om - M);
    m = M;
  }
  __shared__ float rm[4], rs[4];
  if ((threadIdx.x & 63) == 0) { rm[threadIdx.x >> 6] = m; rs[threadIdx.x >> 6] = s; }
  __syncthreads();
  float M = fmaxf(fmaxf(rm[0], rm[1]), fmaxf(rm[2], rm[3]));
  float S = rs[0] * __expf(rm[0] - M) + rs[1] * __expf(rm[1] - M) +
            rs[2] * __expf(rm[2] - M) + rs[3] * __expf(rm[3] - M);
  float lse = M + __logf(S);
  for (int j = threadIdx.x; j < 8000; j += 256) {
    float4 v = *(const float4*)(lr + (long)j * 4);
    v.x -= lse; v.y -= lse; v.z -= lse; v.w -= lse;
    *(float4*)(lr + (long)j * 4) = v;
  }
}

// LDS-cached log_softmax from bf16 logits -> f32 out (nt writes: dead-end stream).
__global__ __launch_bounds__(512) void logsoftmax_bf16_kernel(const u16* __restrict__ lg,
                                                              float* __restrict__ out) {
  __shared__ u16 rl[32000];
  __shared__ float rr[8];
  const long row = blockIdx.x;
  const u16* lr = lg + row * 32000L;
  float* od = out + row * 32000L;
  const int tid = threadIdx.x;
  float m0 = -1e30f, m1 = -1e30f;
  for (int j = tid * 8; j < 32000; j += 4096) {
    ushort4 a = *(const ushort4*)(lr + j);
    ushort4 b = *(const ushort4*)(lr + j + 4);
    *(ushort4*)&rl[j] = a;
    *(ushort4*)&rl[j + 4] = b;
    m0 = fmaxf(m0, fmaxf(fmaxf(bf2f(a.x), bf2f(a.y)), fmaxf(bf2f(a.z), bf2f(a.w))));
    m1 = fmaxf(m1, fmaxf(fmaxf(bf2f(b.x), bf2f(b.y)), fmaxf(bf2f(b.z), bf2f(b.w))));
  }
  float m = wredmax(fmaxf(m0, m1));
  if ((tid & 63) == 0) rr[tid >> 6] = m;
  __syncthreads();
  m = fmaxf(fmaxf(fmaxf(rr[0], rr[1]), fmaxf(rr[2], rr[3])),
            fmaxf(fmaxf(rr[4], rr[5]), fmaxf(rr[6], rr[7])));
  __syncthreads();
  float s0 = 0.f, s1 = 0.f;
  for (int j = tid * 8; j < 32000; j += 4096) {
    ushort4 a = *(const ushort4*)&rl[j];
    ushort4 b = *(const ushort4*)&rl[j + 4];
    s0 += __expf(bf2f(a.x) - m) + __expf(bf2f(a.y) - m) +
          __expf(bf2f(a.z) - m) + __expf(bf2f(a.w) - m);
    s1 += __expf(bf2f(b.x) - m) + __expf(bf2f(b.y) - m) +
          __expf(bf2f(b.z) - m) + __expf(bf2f(b.w) - m);
  }
  float s = wredsum(s0 + s1);
  if ((tid & 63) == 0) rr[tid >> 6] = s;
  __syncthreads();
  s = rr[0] + rr[1] + rr[2] + rr[3] + rr[4] + rr[5] + rr[6] + rr[7];
  const float lse = m + __logf(s);
  for (int j = tid * 8; j < 32000; j += 4096) {
    ushort4 a = *(const ushort4*)&rl[j];
    ushort4 b = *(const ushort4*)&rl[j + 4];
    f32x4 o0 = {bf2f(a.x) - lse, bf2f(a.y) - lse, bf2f(a.z) - lse, bf2f(a.w) - lse};
    f32x4 o1 = {bf2f(b.x) - lse, bf2f(b.y) - lse, bf2f(b.z) - lse, bf2f(b.w) - lse};
    __builtin_nontemporal_store(o0, (f32x4*)(od + j));
    __builtin_nontemporal_store(o1, (f32x4*)(od + j + 4));
  }
}

// ---------------- fused flash attention (LDS-staged, double-buffered) ----------------
// Q [BH,512,64], K [BH,SKV,64], V^T [BH,64,SKV] bf16; out ctx [b,t,h*64+dk].
// One __syncthreads per kv-tile: stage tile t+1 into buf^1, compute tile t from buf,
// barrier (drains vmcnt+lgkmcnt). Exact defer-max skips O-rescale when max unchanged.
template <int SKV>
__global__ __launch_bounds__(256) void attn_kernel(const u16* __restrict__ Q,
                                                   const u16* __restrict__ Kb,
                                                   const u16* __restrict__ Vt,
                                                   u16* __restrict__ ctx) {
  __shared__ u16 Kl[2][4096];    // [buf][64 kv][64 dk], chunk-XOR-swizzled
  __shared__ u16 Vl[2][4096];    // [buf][64 dk][64 kv]
  __shared__ u16 Pl[4][16][72];  // per-wave P: [q][kv]
  const int tid = threadIdx.x, lane = tid & 63, wave = tid >> 6;
  const int l15 = lane & 15, lg = lane >> 4;
  const int bh = blockIdx.y;
  const int qrow = blockIdx.x * 64 + wave * 16 + l15;
  const u16* qp = Q + ((long)bh * 512 + qrow) * 64 + lg * 8;
  bfx8 qf0 = *(const bfx8*)(qp);
  bfx8 qf1 = *(const bfx8*)(qp + 32);

  const int srow = tid >> 3;
  const int schunk = (tid & 7) ^ (srow & 7);
  const u16* Kbb = Kb + ((long)bh * SKV + srow) * 64 + schunk * 8;
  const u16* Vtb2 = Vt + ((long)bh * 64 + srow) * SKV + schunk * 8;

  auto stage = [&](int t, int buf) {
    const int kv0 = t * 64;
    gload16(Kbb + (long)kv0 * 64, &Kl[buf][tid * 8]);
    gload16(Kbb + (long)(kv0 + 32) * 64, &Kl[buf][2048 + tid * 8]);
    gload16(Vtb2 + kv0, &Vl[buf][tid * 8]);
    gload16(Vtb2 + (long)32 * SKV + kv0, &Vl[buf][2048 + tid * 8]);
  };

  const f32x4 zf = {0.f, 0.f, 0.f, 0.f};
  f32x4 acc_o[4] = {zf, zf, zf, zf};
  float mrun = -1e30f, lrun = 0.f;
  const int swk = l15 & 7;
  constexpr int NT = SKV / 64;

  stage(0, 0);
  __syncthreads();
  int buf = 0;
#pragma unroll 1
  for (int t = 0; t < NT; ++t) {
    if (t + 1 < NT) stage(t + 1, buf ^ 1);  // overlaps with compute below
    // S^T tile: lane holds S[q=l15][kv=kvt*16+lg*4+r]
    f32x4 sacc[4];
#pragma unroll
    for (int kvt = 0; kvt < 4; ++kvt) {
      const int krow = kvt * 16 + l15;
      bfx8 kf0 = *(const bfx8*)&Kl[buf][krow * 64 + ((lg ^ swk) << 3)];
      bfx8 kf1 = *(const bfx8*)&Kl[buf][krow * 64 + (((4 + lg) ^ swk) << 3)];
      f32x4 tt = __builtin_amdgcn_mfma_f32_16x16x32_bf16(kf0, qf0, zf, 0, 0, 0);
      sacc[kvt] = __builtin_amdgcn_mfma_f32_16x16x32_bf16(kf1, qf1, tt, 0, 0, 0);
    }
    // online softmax (q = l15; reduce over lg groups)
    float pm = -1e30f;
#pragma unroll
    for (int kvt = 0; kvt < 4; ++kvt)
#pragma unroll
      for (int r = 0; r < 4; ++r) pm = fmaxf(pm, sacc[kvt][r]);
    pm = fmaxf(pm, __shfl_xor(pm, 16, 64));
    pm = fmaxf(pm, __shfl_xor(pm, 32, 64));
    pm *= 0.125f;
    const bool grow = !__all(pm <= mrun);  // exact defer: skip rescale if max unchanged
    const float mnew = grow ? fmaxf(mrun, pm) : mrun;
    float psum = 0.f;
#pragma unroll
    for (int kvt = 0; kvt < 4; ++kvt)
#pragma unroll
      for (int r = 0; r < 4; ++r) {
        float p = __expf(sacc[kvt][r] * 0.125f - mnew);
        psum += p;
        Pl[wave][l15][kvt * 16 + lg * 4 + r] = f2bf(p);
      }
    psum += __shfl_xor(psum, 16, 64);
    psum += __shfl_xor(psum, 32, 64);
    if (grow) {
      const float corr = __expf(mrun - mnew);
      lrun = lrun * corr + psum;
      mrun = mnew;
#pragma unroll
      for (int dt = 0; dt < 4; ++dt) {
        acc_o[dt][0] *= corr; acc_o[dt][1] *= corr;
        acc_o[dt][2] *= corr; acc_o[dt][3] *= corr;
      }
    } else {
      lrun += psum;
    }
    // O^T += V^T-frag x P-frag
    bfx8 pf0 = *(const bfx8*)&Pl[wave][l15][lg * 8];
    bfx8 pf1 = *(const bfx8*)&Pl[wave][l15][32 + lg * 8];
#pragma unroll
    for (int dt = 0; dt < 4; ++dt) {
      const int vrow = dt * 16 + l15;
      bfx8 vf0 = *(const bfx8*)&Vl[buf][vrow * 64 + ((lg ^ swk) << 3)];
      bfx8 vf1 = *(const bfx8*)&Vl[buf][vrow * 64 + (((4 + lg) ^ swk) << 3)];
      acc_o[dt] = __builtin_amdgcn_mfma_f32_16x16x32_bf16(vf0, pf0, acc_o[dt], 0, 0, 0);
      acc_o[dt] = __builtin_amdgcn_mfma_f32_16x16x32_bf16(vf1, pf1, acc_o[dt], 0, 0, 0);
    }
    __syncthreads();  // drains staging vmcnt + ensures buf reads done before overwrite
    buf ^= 1;
  }
  const float inv = 1.0f / lrun;
  const int b = bh >> 4, hh = bh & 15;
  u16* crow = ctx + ((long)b * 512 + qrow) * 1024 + hh * 64;
#pragma unroll
  for (int dt = 0; dt < 4; ++dt)
#pragma unroll
    for (int r = 0; r < 4; ++r)
      crow[dt * 16 + lg * 4 + r] = f2bf(acc_o[dt][r] * inv);
}

// ---------------- 128x128 GEMM (2-barrier, m97 structure) ----------------
// z = K-split index; bias only for z==0. EPI: 0=f32 rm, 1=bf16 rm, 3=bf16 [b,h,t,dk]
template <int BM, int BN, int WMW, int WNW, int EPI, bool RELU>
__global__ __launch_bounds__(256) void gemm_bt(const u16* __restrict__ A, long sAz, int lda,
                                               const u16* __restrict__ Bt, long sBz, int ldb,
                                               const float* __restrict__ bias,
                                               void* __restrict__ out, long sCz, int ldc,
                                               int K, int Ttok) {
  constexpr int WROWS = BM / WMW, WCOLS = BN / WNW;
  constexpr int MI = WROWS / 16, NI = WCOLS / 16;
  __shared__ u16 As[BM * 32];
  __shared__ u16 Bs[BN * 32];
  const int tid = threadIdx.x, lane = tid & 63, wave = tid >> 6;
  const int l15 = lane & 15, lg = lane >> 4;
  const int wm = wave / WNW, wn = wave % WNW;
  const int bx = blockIdx.x, by = blockIdx.y;
  const long z = blockIdx.z;
  const int srow = tid >> 2, scol = (tid & 3) << 3;
  const u16* Aa = A + z * sAz + (long)(by * BM + srow) * lda + scol;
  const u16* Ba = Bt + z * sBz + (long)(bx * BN + srow) * ldb + scol;

  f32x4 acc[MI][NI];
#pragma unroll
  for (int i = 0; i < MI; ++i)
#pragma unroll
    for (int j = 0; j < NI; ++j) acc[i][j] = (f32x4){0.f, 0.f, 0.f, 0.f};

  for (int kt = 0; kt < K; kt += 32) {
#pragma unroll
    for (int i = 0; i < BM / 64; ++i)
      gload16(Aa + (long)i * 64 * lda + kt, &As[i * 2048 + tid * 8]);
#pragma unroll
    for (int i = 0; i < BN / 64; ++i)
      gload16(Ba + (long)i * 64 * ldb + kt, &Bs[i * 2048 + tid * 8]);
    __syncthreads();
    bfx8 afr[MI], bfr[NI];
#pragma unroll
    for (int i = 0; i < MI; ++i)
      afr[i] = *(const bfx8*)&As[(wm * WROWS + i * 16 + l15) * 32 + (lg << 3)];
#pragma unroll
    for (int j = 0; j < NI; ++j)
      bfr[j] = *(const bfx8*)&Bs[(wn * WCOLS + j * 16 + l15) * 32 + (lg << 3)];
#pragma unroll
    for (int i = 0; i < MI; ++i)
#pragma unroll
      for (int j = 0; j < NI; ++j)
        acc[i][j] = __builtin_amdgcn_mfma_f32_16x16x32_bf16(afr[i], bfr[j], acc[i][j], 0, 0, 0);
    __syncthreads();
  }

  const int gm0 = by * BM + wm * WROWS;
  const int gn0 = bx * BN + wn * WCOLS;
#pragma unroll
  for (int i = 0; i < MI; ++i) {
#pragma unroll
    for (int j = 0; j < NI; ++j) {
      const int gn = gn0 + j * 16 + l15;
      const float bv = (bias && z == 0) ? bias[gn] : 0.f;
#pragma unroll
      for (int r = 0; r < 4; ++r) {
        const int gm = gm0 + i * 16 + (lg << 2) + r;
        float v = acc[i][j][r] + bv;
        if (RELU) v = fmaxf(v, 0.f);
        if constexpr (EPI == 0) {
          ((float*)out)[z * sCz + (long)gm * ldc + gn] = v;
        } else if constexpr (EPI == 1) {
          ((u16*)out)[z * sCz + (long)gm * ldc + gn] = f2bf(v);
        } else if constexpr (EPI == 3) {
          const int b = gm / Ttok, t = gm - b * Ttok;
          const int hh = gn >> 6, dk = gn & 63;
          ((u16*)out)[(((long)(b * 16 + hh) * Ttok + t) << 6) + dk] = f2bf(v);
        }
      }
    }
  }
}

// ---------------- 256x256 8-phase GEMM (T2+T3+T4+T5) ----------------
// NTS: non-temporal stores for EPI==1 (dead-end logit stream; protects L3 B panels)
#define MMAQ(hm, hn)                                                                   \
  {                                                                                    \
    _Pragma("unroll") for (int kk = 0; kk < 2; ++kk)                                   \
        _Pragma("unroll") for (int i = 0; i < 4; ++i)                                  \
            _Pragma("unroll") for (int jn = 0; jn < 2; ++jn)                           \
                acc[(hm)*4 + i][(hn)*2 + jn] = __builtin_amdgcn_mfma_f32_16x16x32_bf16( \
                    a[i][kk], b[jn][kk], acc[(hm)*4 + i][(hn)*2 + jn], 0, 0, 0);       \
  }

template <int EPI, bool RELU, bool NTS>
__global__ __launch_bounds__(512, 2) void gemm256(const u16* __restrict__ A, int lda,
                                                  const u16* __restrict__ Bt, int ldb,
                                                  const float* __restrict__ bias,
                                                  void* __restrict__ out, int ldc, int K,
                                                  int Ttok, void* __restrict__ out2,
                                                  void* __restrict__ out3, int gx) {
  __shared__ u16 lds[2][2][2][8192];  // [dbuf][A/B][half][128*64]
  const int tid = threadIdx.x, lane = tid & 63;
  const int wid = tid >> 6, wm = wid >> 2, wn = wid & 3;
  const int l15 = lane & 15, lg = lane >> 4;
  const int mt = blockIdx.x % gx;
  const int nt_ = blockIdx.x / gx;
  const int NT = K >> 6;

  const int r0 = tid >> 3;
  const int blkx = (tid & 7) ^ (r0 & 7);
  const u16* Abase = A + (long)(mt * 256 + r0) * lda + blkx * 8;
  const u16* Bbase = Bt + (long)(nt_ * 256 + r0) * ldb + blkx * 8;

  auto stageA = [&](int s, int half) {
    const int kts = (s < NT ? s : NT - 1) << 6;
    const u16* g = Abase + (long)(half * 128) * lda + kts;
    gload16(g, &lds[s & 1][0][half][tid * 8]);
    gload16(g + (long)64 * lda, &lds[s & 1][0][half][(512 + tid) * 8]);
  };
  auto stageB = [&](int s, int half) {
    const int kts = (s < NT ? s : NT - 1) << 6;
    const u16* g = Bbase + (long)(half * 128) * ldb + kts;
    gload16(g, &lds[s & 1][1][half][tid * 8]);
    gload16(g + (long)64 * ldb, &lds[s & 1][1][half][(512 + tid) * 8]);
  };

  f32x4 acc[8][4];
#pragma unroll
  for (int i = 0; i < 8; ++i)
#pragma unroll
    for (int j = 0; j < 4; ++j) acc[i][j] = (f32x4){0.f, 0.f, 0.f, 0.f};
  bfx8 a[4][2], b[2][2];

  const int sw = l15 & 7;
  auto loadA = [&](int buf, int hm) {
#pragma unroll
    for (int i = 0; i < 4; ++i) {
      const int row = hm * 64 + i * 16 + l15;
#pragma unroll
      for (int kk = 0; kk < 2; ++kk)
        a[i][kk] = *(const bfx8*)&lds[buf][0][wm][row * 64 + (((kk * 4 + lg) ^ sw) << 3)];
    }
  };
  auto loadB = [&](int buf, int hn) {
#pragma unroll
    for (int jn = 0; jn < 2; ++jn) {
      const int row = (wn & 1) * 64 + hn * 32 + jn * 16 + l15;
#pragma unroll
      for (int kk = 0; kk < 2; ++kk)
        b[jn][kk] = *(const bfx8*)&lds[buf][1][wn >> 1][row * 64 + (((kk * 4 + lg) ^ sw) << 3)];
    }
  };

  stageA(0, 0); stageA(0, 1); stageB(0, 0); stageB(0, 1);
  stageA(1, 0); stageA(1, 1);
  asm volatile("s_waitcnt vmcnt(4)" ::: "memory");
  __builtin_amdgcn_s_barrier();

  for (int t = 0; t < NT; ++t) {
    const int p = t & 1;
    loadA(p, 0); loadB(p, 0);
    stageB(t + 1, 0);
    __builtin_amdgcn_s_barrier();
    asm volatile("s_waitcnt lgkmcnt(0)" ::: "memory");
    __builtin_amdgcn_s_setprio(1);
    MMAQ(0, 0);
    __builtin_amdgcn_s_setprio(0);
    __builtin_amdgcn_s_barrier();
    loadB(p, 1);
    stageB(t + 1, 1);
    __builtin_amdgcn_s_barrier();
    asm volatile("s_waitcnt lgkmcnt(0)" ::: "memory");
    __builtin_amdgcn_s_setprio(1);
    MMAQ(0, 1);
    __builtin_amdgcn_s_setprio(0);
    __builtin_amdgcn_s_barrier();
    loadA(p, 1); loadB(p, 0);
    stageA(t + 2, 0);
    __builtin_amdgcn_s_barrier();
    asm volatile("s_waitcnt lgkmcnt(0)" ::: "memory");
    __builtin_amdgcn_s_setprio(1);
    MMAQ(1, 0);
    __builtin_amdgcn_s_setprio(0);
    __builtin_amdgcn_s_barrier();
    loadB(p, 1);
    stageA(t + 2, 1);
    asm volatile("s_waitcnt vmcnt(4)" ::: "memory");
    __builtin_amdgcn_s_barrier();
    asm volatile("s_waitcnt lgkmcnt(0)" ::: "memory");
    __builtin_amdgcn_s_setprio(1);
    MMAQ(1, 1);
    __builtin_amdgcn_s_setprio(0);
    __builtin_amdgcn_s_barrier();
  }

  const int gm0 = mt * 256 + wm * 128;
  const int gn0 = nt_ * 256 + wn * 64;
#pragma unroll
  for (int ii = 0; ii < 8; ++ii) {
#pragma unroll
    for (int jj = 0; jj < 4; ++jj) {
      const int gn = gn0 + jj * 16 + l15;
      const float bv = bias ? bias[gn] : 0.f;
#pragma unroll
      for (int r = 0; r < 4; ++r) {
        const int gm = gm0 + ii * 16 + (lg << 2) + r;
        float v = acc[ii][jj][r] + bv;
        if (RELU) v = fmaxf(v, 0.f);
        if constexpr (EPI == 0) {
          ((float*)out)[(long)gm * ldc + gn] = v;
        } else if constexpr (EPI == 1) {
          if constexpr (NTS)
            __builtin_nontemporal_store(f2bf(v), &((u16*)out)[(long)gm * ldc + gn]);
          else
            ((u16*)out)[(long)gm * ldc + gn] = f2bf(v);
        } else if constexpr (EPI == 6) {
          const int bq = gm / Ttok, t2 = gm - bq * Ttok;
          const int sec = gn >> 10, w1 = gn & 1023;
          const int hh = w1 >> 6, dk = w1 & 63;
          const u16 val = f2bf(v);
          if (sec == 0)
            ((u16*)out)[(((long)(bq * 16 + hh) * Ttok + t2) << 6) + dk] = val;
          else if (sec == 1)
            ((u16*)out2)[(((long)(bq * 16 + hh) * Ttok + t2) << 6) + dk] = val;
          else
            ((u16*)out3)[((long)((bq * 16 + hh) << 6) + dk) * Ttok + t2] = val;
        } else if constexpr (EPI == 7) {
          const int bq = gm / Ttok, t2 = gm - bq * Ttok;
          const int sec = gn >> 10, w1 = gn & 1023;
          const int hh = w1 >> 6, dk = w1 & 63;
          const u16 val = f2bf(v);
          if (sec == 0)
            ((u16*)out)[(((long)(bq * 16 + hh) * Ttok + t2) << 6) + dk] = val;
          else
            ((u16*)out2)[((long)((bq * 16 + hh) << 6) + dk) * Ttok + t2] = val;
        }
      }
    }
  }
}

// ---------------- driver ----------------
extern "C" void kernel_launch(void* const* d_in, const int* in_sizes, int n_in,
                              void* d_out, int out_size, void* d_ws, size_t ws_size,
                              hipStream_t stream) {
  const int* x = (const int*)d_in[0];
  const float* enc = (const float*)d_in[1];
  const float* emb = (const float*)d_in[2];
  const float* pe = (const float*)d_in[3];
  const float* a1w = (const float*)d_in[4];
  const float* a1b = (const float*)d_in[5];
  const float* a2w = (const float*)d_in[6];
  const float* a2b = (const float*)d_in[7];
  const float* nra = (const float*)d_in[8];
  const float* nrb = (const float*)d_in[9];
  const float* f1w = (const float*)d_in[10];
  const float* f1b = (const float*)d_in[11];
  const float* f2w = (const float*)d_in[12];
  const float* f2b = (const float*)d_in[13];
  const float* fcw = (const float*)d_in[14];
  const float* fcb = (const float*)d_in[15];
  float* out = (float*)d_out;

  char* base = (char*)d_ws;
  size_t off = 0;
  auto alloc = [&](size_t bytes) -> void* {
    void* p = base + off;
    off += (bytes + 255) & ~(size_t)255;
    return p;
  };
  const long wsz = 1024 * 1024;
  const bool big = ws_size >= (600ull << 20);
  u16* wT = (u16*)alloc(96ull * wsz * 2);    // all transposed weights: a1|a2|f1|f2
  u16* encb = (u16*)alloc(8ull * wsz * 2);   // encoder bf16 [8192,1024]
  float* h = (float*)alloc(4ull * wsz * 4);  // residual f32 [4096,1024]
  u16* hb = (u16*)alloc(4ull * wsz * 2);     // bf16 copy of h
  u16* qb = (u16*)alloc(4ull * wsz * 2);     // [B,H,512,64]
  u16* kb = (u16*)alloc(8ull * wsz * 2);     // [B,H,<=1024,64]
  u16* vtb = (u16*)alloc(8ull * wsz * 2);    // [B,H,64,<=1024]
  u16* ctxb = (u16*)alloc(4ull * wsz * 2);   // [4096,1024] bf16
  float* af = (float*)alloc(4ull * wsz * 4); // K-split partial 0
  float* af2 = (float*)alloc(4ull * wsz * 4);// K-split partial 1
  u16* midb = (u16*)alloc(16ull * wsz * 2);  // FFN mid bf16 [4096,4096]
  u16* fcT = qb;                             // fc^T (64 MB) aliases qb.. after layers
  u16* lgb = big ? (u16*)alloc(4096ull * 32000 * 2) : nullptr;  // bf16 logits

  u16* wTa1 = wT;               // [L][4][1024][1024]^T
  u16* wTa2 = wT + 24 * wsz;
  u16* wTf1 = wT + 48 * wsz;    // [L][4096][1024]
  u16* wTf2 = wT + 72 * wsz;    // [L][1024][4096]

  cvt_kernel<<<dim3(8192), dim3(256), 0, stream>>>(enc, encb, 8ll * wsz);
  embed_kernel<<<dim3(4096), dim3(256), 0, stream>>>(x, emb, pe, h, hb);
  wconv_kernel<<<dim3(32, 32, 24), dim3(256), 0, stream>>>(a1w, wTa1, 1024, 1024);
  wconv_kernel<<<dim3(32, 32, 24), dim3(256), 0, stream>>>(a2w, wTa2, 1024, 1024);
  wconv_kernel<<<dim3(128, 32, 6), dim3(256), 0, stream>>>(f1w, wTf1, 1024, 4096);
  wconv_kernel<<<dim3(32, 128, 6), dim3(256), 0, stream>>>(f2w, wTf2, 4096, 1024);

  for (int l = 0; l < 6; ++l) {
    const float* b1 = a1b + (long)l * 4096;
    const float* b2 = a2b + (long)l * 4096;
    const u16* w1 = wTa1 + (long)l * 4 * wsz;
    const u16* w2 = wTa2 + (long)l * 4 * wsz;

    // ---- self attention ----
    gemm256<6, false, false><<<dim3(192), dim3(512), 0, stream>>>(
        hb, 1024, w1, 1024, b1, qb, 0, 1024, 512, kb, vtb, 16);
    attn_kernel<512><<<dim3(8, 128), dim3(256), 0, stream>>>(qb, kb, vtb, ctxb);
    gemm_bt<128, 128, 2, 2, 0, false><<<dim3(8, 32, 2), dim3(256), 0, stream>>>(
        ctxb, 512, 1024, w1 + 3 * wsz, 512, 1024, b1 + 3072, af, 4194304, 1024, 512, 0);
    addnorm_kernel<<<dim3(4096), dim3(256), 0, stream>>>(
        af, af2, h, hb, nra + (l * 3 + 0) * 1024, nrb + (l * 3 + 0) * 1024);

    // ---- cross attention ----
    gemm_bt<128, 128, 2, 2, 3, false><<<dim3(8, 32, 1), dim3(256), 0, stream>>>(
        hb, 0, 1024, w2, 0, 1024, b2, qb, 0, 0, 1024, 512);
    gemm256<7, false, false><<<dim3(256), dim3(512), 0, stream>>>(
        encb, 1024, w2 + wsz, 1024, b2 + 1024, kb, 0, 1024, 1024, vtb, nullptr, 32);
    attn_kernel<1024><<<dim3(8, 128), dim3(256), 0, stream>>>(qb, kb, vtb, ctxb);
    gemm_bt<128, 128, 2, 2, 0, false><<<dim3(8, 32, 2), dim3(256), 0, stream>>>(
        ctxb, 512, 1024, w2 + 3 * wsz, 512, 1024, b2 + 3072, af, 4194304, 1024, 512, 0);
    addnorm_kernel<<<dim3(4096), dim3(256), 0, stream>>>(
        af, af2, h, hb, nra + (l * 3 + 1) * 1024, nrb + (l * 3 + 1) * 1024);

    // ---- ffn ----
    gemm256<1, true, false><<<dim3(256), dim3(512), 0, stream>>>(
        hb, 1024, wTf1 + (long)l * 4 * wsz, 1024, f1b + (long)l * 4096, midb, 4096, 1024, 0,
        nullptr, nullptr, 16);
    gemm_bt<128, 128, 2, 2, 0, false><<<dim3(8, 32, 2), dim3(256), 0, stream>>>(
        midb, 2048, 4096, wTf2 + (long)l * 4 * wsz, 2048, 4096, f2b + (long)l * 1024, af,
        4194304, 1024, 2048, 0);
    addnorm_kernel<<<dim3(4096), dim3(256), 0, stream>>>(
        af, af2, h, hb, nra + (l * 3 + 2) * 1024, nrb + (l * 3 + 2) * 1024);
  }

  // final projection + log_softmax
  wconv_kernel<<<dim3(1000, 32, 1), dim3(256), 0, stream>>>(fcw, fcT, 1024, 32000);
  if (big) {
    gemm256<1, false, true><<<dim3(2000), dim3(512), 0, stream>>>(
        hb, 1024, fcT, 1024, fcb, lgb, 32000, 1024, 0, nullptr, nullptr, 16);
    logsoftmax_bf16_kernel<<<dim3(4096), dim3(512), 0, stream>>>(lgb, out);
  } else {
    gemm256<0, false, false><<<dim3(2000), dim3(512), 0, stream>>>(
        hb, 1024, fcT, 1024, fcb, out, 32000, 1024, 0, nullptr, nullptr, 16);
    logsoftmax_kernel<<<dim3(4096), dim3(256), 0, stream>>>(out);
  }
}

// Round 9
// 3304.609 us; speedup vs baseline: 1.1682x; 1.0332x over previous
//
#include <hip/hip_runtime.h>

typedef __attribute__((ext_vector_type(4))) float f32x4;
typedef __attribute__((ext_vector_type(8))) __bf16 bfx8;
typedef unsigned short u16;
typedef unsigned int u32;

// ---------------- helpers ----------------
__device__ __forceinline__ u16 f2bf(float f) {
  u32 u = __builtin_bit_cast(u32, f);
  u = (u + 0x7FFFu + ((u >> 16) & 1u)) >> 16;
  return (u16)u;
}
__device__ __forceinline__ float bf2f(u16 u) {
  return __builtin_bit_cast(float, ((u32)u) << 16);
}

typedef __attribute__((address_space(1))) const void gvoid;
typedef __attribute__((address_space(3))) void svoid;
__device__ __forceinline__ void gload16(const void* g, void* l) {
  __builtin_amdgcn_global_load_lds((gvoid*)g, (svoid*)l, 16, 0, 0);
}

__device__ __forceinline__ float wredsum(float v) {
#pragma unroll
  for (int o = 32; o; o >>= 1) v += __shfl_xor(v, o, 64);
  return v;
}
__device__ __forceinline__ float wredmax(float v) {
#pragma unroll
  for (int o = 32; o; o >>= 1) v = fmaxf(v, __shfl_xor(v, o, 64));
  return v;
}

// ---------------- small kernels ----------------
// fp32 [z][K][N] -> bf16 [z][N][K]
__global__ __launch_bounds__(256) void wconv_kernel(const float* __restrict__ in,
                                                    u16* __restrict__ out, int K, int N) {
  __shared__ u16 tile[32][33];
  const long z = blockIdx.z;
  const float* iz = in + z * (long)K * N;
  u16* oz = out + z * (long)K * N;
  const int n0 = blockIdx.x << 5, k0 = blockIdx.y << 5;
  const int tx = threadIdx.x & 31, ty = threadIdx.x >> 5;
#pragma unroll
  for (int i = 0; i < 4; ++i)
    tile[ty + 8 * i][tx] = f2bf(iz[(long)(k0 + ty + 8 * i) * N + n0 + tx]);
  __syncthreads();
#pragma unroll
  for (int i = 0; i < 4; ++i)
    oz[(long)(n0 + ty + 8 * i) * K + k0 + tx] = tile[tx][ty + 8 * i];
}

__global__ __launch_bounds__(256) void cvt_kernel(const float* __restrict__ in,
                                                  u16* __restrict__ out, long n) {
  long i = ((long)blockIdx.x * 256 + threadIdx.x) * 4;
  if (i + 3 < n) {
    float4 v = *(const float4*)(in + i);
    ushort4 o = {f2bf(v.x), f2bf(v.y), f2bf(v.z), f2bf(v.w)};
    *(ushort4*)(out + i) = o;
  }
}

__global__ __launch_bounds__(256) void embed_kernel(const int* __restrict__ x,
                                                    const float* __restrict__ emb,
                                                    const float* __restrict__ pe,
                                                    float* __restrict__ h,
                                                    u16* __restrict__ hb) {
  const int row = blockIdx.x;
  const int b = row >> 9, t = row & 511;
  const long tok = (long)x[b * 513 + t];
  const int d = threadIdx.x << 2;
  float4 e = *(const float4*)(emb + tok * 1024 + d);
  float4 p = *(const float4*)(pe + (long)t * 1024 + d);
  float4 v = {e.x + p.x, e.y + p.y, e.z + p.z, e.w + p.w};
  *(float4*)(h + (long)row * 1024 + d) = v;
  ushort4 o = {f2bf(v.x), f2bf(v.y), f2bf(v.z), f2bf(v.w)};
  *(ushort4*)(hb + (long)row * 1024 + d) = o;
}

// h = norm(h + delta + delta2); single-pass dual reduction
__global__ __launch_bounds__(256) void addnorm_kernel(const float* __restrict__ delta,
                                                      const float* __restrict__ delta2,
                                                      float* __restrict__ h,
                                                      u16* __restrict__ hb,
                                                      const float* __restrict__ ga,
                                                      const float* __restrict__ gb) {
  __shared__ float r1[4], r2[4];
  const long row = blockIdx.x;
  const int d = threadIdx.x << 2;
  float4 a = *(const float4*)(h + row * 1024 + d);
  float4 q = *(const float4*)(delta + row * 1024 + d);
  float4 q2 = *(const float4*)(delta2 + row * 1024 + d);
  float x0 = a.x + q.x + q2.x, x1 = a.y + q.y + q2.y;
  float x2 = a.z + q.z + q2.z, x3 = a.w + q.w + q2.w;
  float s1 = wredsum(x0 + x1 + x2 + x3);
  float s2 = wredsum(x0 * x0 + x1 * x1 + x2 * x2 + x3 * x3);
  if ((threadIdx.x & 63) == 0) { r1[threadIdx.x >> 6] = s1; r2[threadIdx.x >> 6] = s2; }
  __syncthreads();
  float S1 = r1[0] + r1[1] + r1[2] + r1[3];
  float S2 = r2[0] + r2[1] + r2[2] + r2[3];
  float mu = S1 * (1.0f / 1024.0f);
  float var = (S2 - S1 * mu) * (1.0f / 1023.0f);
  float inv = 1.0f / (sqrtf(fmaxf(var, 0.f)) + 1e-6f);
  float4 g4 = *(const float4*)(ga + d);
  float4 b4 = *(const float4*)(gb + d);
  float y0 = g4.x * (x0 - mu) * inv + b4.x;
  float y1 = g4.y * (x1 - mu) * inv + b4.y;
  float y2 = g4.z * (x2 - mu) * inv + b4.z;
  float y3 = g4.w * (x3 - mu) * inv + b4.w;
  float4 y = {y0, y1, y2, y3};
  *(float4*)(h + row * 1024 + d) = y;
  ushort4 o = {f2bf(y0), f2bf(y1), f2bf(y2), f2bf(y3)};
  *(ushort4*)(hb + row * 1024 + d) = o;
}

// in-place log_softmax over rows of 32000 fp32 (fallback)
__global__ __launch_bounds__(256) void logsoftmax_kernel(float* __restrict__ lg) {
  const long row = blockIdx.x;
  float* lr = lg + row * 32000L;
  float m = -1e30f, s = 0.f;
  for (int j = threadIdx.x; j < 8000; j += 256) {
    float4 v = *(const float4*)(lr + (long)j * 4);
    float lm = fmaxf(fmaxf(v.x, v.y), fmaxf(v.z, v.w));
    if (lm > m) { s *= __expf(m - lm); m = lm; }
    s += __expf(v.x - m) + __expf(v.y - m) + __expf(v.z - m) + __expf(v.w - m);
  }
#pragma unroll
  for (int o = 32; o; o >>= 1) {
    float om = __shfl_xor(m, o, 64), os = __shfl_xor(s, o, 64);
    float M = fmaxf(m, om);
    s = s * __expf(m - M) + os * __expf(om - M);
    m = M;
  }
  __shared__ float rm[4], rs[4];
  if ((threadIdx.x & 63) == 0) { rm[threadIdx.x >> 6] = m; rs[threadIdx.x >> 6] = s; }
  __syncthreads();
  float M = fmaxf(fmaxf(rm[0], rm[1]), fmaxf(rm[2], rm[3]));
  float S = rs[0] * __expf(rm[0] - M) + rs[1] * __expf(rm[1] - M) +
            rs[2] * __expf(rm[2] - M) + rs[3] * __expf(rm[3] - M);
  float lse = M + __logf(S);
  for (int j = threadIdx.x; j < 8000; j += 256) {
    float4 v = *(const float4*)(lr + (long)j * 4);
    v.x -= lse; v.y -= lse; v.z -= lse; v.w -= lse;
    *(float4*)(lr + (long)j * 4) = v;
  }
}

// LDS-cached log_softmax from bf16 logits -> f32 out.
__global__ __launch_bounds__(512) void logsoftmax_bf16_kernel(const u16* __restrict__ lg,
                                                              float* __restrict__ out) {
  __shared__ u16 rl[32000];
  __shared__ float rr[8];
  const long row = blockIdx.x;
  const u16* lr = lg + row * 32000L;
  float* od = out + row * 32000L;
  const int tid = threadIdx.x;
  float m0 = -1e30f, m1 = -1e30f;
  for (int j = tid * 8; j < 32000; j += 4096) {
    ushort4 a = *(const ushort4*)(lr + j);
    ushort4 b = *(const ushort4*)(lr + j + 4);
    *(ushort4*)&rl[j] = a;
    *(ushort4*)&rl[j + 4] = b;
    m0 = fmaxf(m0, fmaxf(fmaxf(bf2f(a.x), bf2f(a.y)), fmaxf(bf2f(a.z), bf2f(a.w))));
    m1 = fmaxf(m1, fmaxf(fmaxf(bf2f(b.x), bf2f(b.y)), fmaxf(bf2f(b.z), bf2f(b.w))));
  }
  float m = wredmax(fmaxf(m0, m1));
  if ((tid & 63) == 0) rr[tid >> 6] = m;
  __syncthreads();
  m = fmaxf(fmaxf(fmaxf(rr[0], rr[1]), fmaxf(rr[2], rr[3])),
            fmaxf(fmaxf(rr[4], rr[5]), fmaxf(rr[6], rr[7])));
  __syncthreads();
  float s0 = 0.f, s1 = 0.f;
  for (int j = tid * 8; j < 32000; j += 4096) {
    ushort4 a = *(const ushort4*)&rl[j];
    ushort4 b = *(const ushort4*)&rl[j + 4];
    s0 += __expf(bf2f(a.x) - m) + __expf(bf2f(a.y) - m) +
          __expf(bf2f(a.z) - m) + __expf(bf2f(a.w) - m);
    s1 += __expf(bf2f(b.x) - m) + __expf(bf2f(b.y) - m) +
          __expf(bf2f(b.z) - m) + __expf(bf2f(b.w) - m);
  }
  float s = wredsum(s0 + s1);
  if ((tid & 63) == 0) rr[tid >> 6] = s;
  __syncthreads();
  s = rr[0] + rr[1] + rr[2] + rr[3] + rr[4] + rr[5] + rr[6] + rr[7];
  const float lse = m + __logf(s);
  for (int j = tid * 8; j < 32000; j += 4096) {
    ushort4 a = *(const ushort4*)&rl[j];
    ushort4 b = *(const ushort4*)&rl[j + 4];
    float4 o0 = {bf2f(a.x) - lse, bf2f(a.y) - lse, bf2f(a.z) - lse, bf2f(a.w) - lse};
    float4 o1 = {bf2f(b.x) - lse, bf2f(b.y) - lse, bf2f(b.z) - lse, bf2f(b.w) - lse};
    *(float4*)(od + j) = o0;
    *(float4*)(od + j + 4) = o1;
  }
}

// ---------------- fused flash attention (LDS-staged, double-buffered) ----------------
// Q [BH,512,64], K [BH,SKV,64], V^T [BH,64,SKV] bf16; out ctx [b,t,h*64+dk].
// One __syncthreads per kv-tile: stage tile t+1 into buf^1, compute tile t from buf,
// barrier (drains vmcnt+lgkmcnt). Exact defer-max skips O-rescale when max unchanged.
template <int SKV>
__global__ __launch_bounds__(256) void attn_kernel(const u16* __restrict__ Q,
                                                   const u16* __restrict__ Kb,
                                                   const u16* __restrict__ Vt,
                                                   u16* __restrict__ ctx) {
  __shared__ u16 Kl[2][4096];    // [buf][64 kv][64 dk], chunk-XOR-swizzled
  __shared__ u16 Vl[2][4096];    // [buf][64 dk][64 kv]
  __shared__ u16 Pl[4][16][72];  // per-wave P: [q][kv]
  const int tid = threadIdx.x, lane = tid & 63, wave = tid >> 6;
  const int l15 = lane & 15, lg = lane >> 4;
  const int bh = blockIdx.y;
  const int qrow = blockIdx.x * 64 + wave * 16 + l15;
  const u16* qp = Q + ((long)bh * 512 + qrow) * 64 + lg * 8;
  bfx8 qf0 = *(const bfx8*)(qp);
  bfx8 qf1 = *(const bfx8*)(qp + 32);

  const int srow = tid >> 3;
  const int schunk = (tid & 7) ^ (srow & 7);
  const u16* Kbb = Kb + ((long)bh * SKV + srow) * 64 + schunk * 8;
  const u16* Vtb2 = Vt + ((long)bh * 64 + srow) * SKV + schunk * 8;

  auto stage = [&](int t, int buf) {
    const int kv0 = t * 64;
    gload16(Kbb + (long)kv0 * 64, &Kl[buf][tid * 8]);
    gload16(Kbb + (long)(kv0 + 32) * 64, &Kl[buf][2048 + tid * 8]);
    gload16(Vtb2 + kv0, &Vl[buf][tid * 8]);
    gload16(Vtb2 + (long)32 * SKV + kv0, &Vl[buf][2048 + tid * 8]);
  };

  const f32x4 zf = {0.f, 0.f, 0.f, 0.f};
  f32x4 acc_o[4] = {zf, zf, zf, zf};
  float mrun = -1e30f, lrun = 0.f;
  const int swk = l15 & 7;
  constexpr int NT = SKV / 64;

  stage(0, 0);
  __syncthreads();
  int buf = 0;
#pragma unroll 1
  for (int t = 0; t < NT; ++t) {
    if (t + 1 < NT) stage(t + 1, buf ^ 1);  // overlaps with compute below
    // S^T tile: lane holds S[q=l15][kv=kvt*16+lg*4+r]
    f32x4 sacc[4];
#pragma unroll
    for (int kvt = 0; kvt < 4; ++kvt) {
      const int krow = kvt * 16 + l15;
      bfx8 kf0 = *(const bfx8*)&Kl[buf][krow * 64 + ((lg ^ swk) << 3)];
      bfx8 kf1 = *(const bfx8*)&Kl[buf][krow * 64 + (((4 + lg) ^ swk) << 3)];
      f32x4 tt = __builtin_amdgcn_mfma_f32_16x16x32_bf16(kf0, qf0, zf, 0, 0, 0);
      sacc[kvt] = __builtin_amdgcn_mfma_f32_16x16x32_bf16(kf1, qf1, tt, 0, 0, 0);
    }
    // online softmax (q = l15; reduce over lg groups)
    float pm = -1e30f;
#pragma unroll
    for (int kvt = 0; kvt < 4; ++kvt)
#pragma unroll
      for (int r = 0; r < 4; ++r) pm = fmaxf(pm, sacc[kvt][r]);
    pm = fmaxf(pm, __shfl_xor(pm, 16, 64));
    pm = fmaxf(pm, __shfl_xor(pm, 32, 64));
    pm *= 0.125f;
    const bool grow = !__all(pm <= mrun);  // exact defer: skip rescale if max unchanged
    const float mnew = grow ? fmaxf(mrun, pm) : mrun;
    float psum = 0.f;
#pragma unroll
    for (int kvt = 0; kvt < 4; ++kvt)
#pragma unroll
      for (int r = 0; r < 4; ++r) {
        float p = __expf(sacc[kvt][r] * 0.125f - mnew);
        psum += p;
        Pl[wave][l15][kvt * 16 + lg * 4 + r] = f2bf(p);
      }
    psum += __shfl_xor(psum, 16, 64);
    psum += __shfl_xor(psum, 32, 64);
    if (grow) {
      const float corr = __expf(mrun - mnew);
      lrun = lrun * corr + psum;
      mrun = mnew;
#pragma unroll
      for (int dt = 0; dt < 4; ++dt) {
        acc_o[dt][0] *= corr; acc_o[dt][1] *= corr;
        acc_o[dt][2] *= corr; acc_o[dt][3] *= corr;
      }
    } else {
      lrun += psum;
    }
    // O^T += V^T-frag x P-frag
    bfx8 pf0 = *(const bfx8*)&Pl[wave][l15][lg * 8];
    bfx8 pf1 = *(const bfx8*)&Pl[wave][l15][32 + lg * 8];
#pragma unroll
    for (int dt = 0; dt < 4; ++dt) {
      const int vrow = dt * 16 + l15;
      bfx8 vf0 = *(const bfx8*)&Vl[buf][vrow * 64 + ((lg ^ swk) << 3)];
      bfx8 vf1 = *(const bfx8*)&Vl[buf][vrow * 64 + (((4 + lg) ^ swk) << 3)];
      acc_o[dt] = __builtin_amdgcn_mfma_f32_16x16x32_bf16(vf0, pf0, acc_o[dt], 0, 0, 0);
      acc_o[dt] = __builtin_amdgcn_mfma_f32_16x16x32_bf16(vf1, pf1, acc_o[dt], 0, 0, 0);
    }
    __syncthreads();  // drains staging vmcnt + ensures buf reads done before overwrite
    buf ^= 1;
  }
  const float inv = 1.0f / lrun;
  const int b = bh >> 4, hh = bh & 15;
  u16* crow = ctx + ((long)b * 512 + qrow) * 1024 + hh * 64;
#pragma unroll
  for (int dt = 0; dt < 4; ++dt)
#pragma unroll
    for (int r = 0; r < 4; ++r)
      crow[dt * 16 + lg * 4 + r] = f2bf(acc_o[dt][r] * inv);
}

// ---------------- 128x128 GEMM (2-barrier, m97 structure) ----------------
// z = K-split index; bias only for z==0. EPI: 0=f32 rm, 1=bf16 rm, 3=bf16 [b,h,t,dk]
template <int BM, int BN, int WMW, int WNW, int EPI, bool RELU>
__global__ __launch_bounds__(256) void gemm_bt(const u16* __restrict__ A, long sAz, int lda,
                                               const u16* __restrict__ Bt, long sBz, int ldb,
                                               const float* __restrict__ bias,
                                               void* __restrict__ out, long sCz, int ldc,
                                               int K, int Ttok) {
  constexpr int WROWS = BM / WMW, WCOLS = BN / WNW;
  constexpr int MI = WROWS / 16, NI = WCOLS / 16;
  __shared__ u16 As[BM * 32];
  __shared__ u16 Bs[BN * 32];
  const int tid = threadIdx.x, lane = tid & 63, wave = tid >> 6;
  const int l15 = lane & 15, lg = lane >> 4;
  const int wm = wave / WNW, wn = wave % WNW;
  const int bx = blockIdx.x, by = blockIdx.y;
  const long z = blockIdx.z;
  const int srow = tid >> 2, scol = (tid & 3) << 3;
  const u16* Aa = A + z * sAz + (long)(by * BM + srow) * lda + scol;
  const u16* Ba = Bt + z * sBz + (long)(bx * BN + srow) * ldb + scol;

  f32x4 acc[MI][NI];
#pragma unroll
  for (int i = 0; i < MI; ++i)
#pragma unroll
    for (int j = 0; j < NI; ++j) acc[i][j] = (f32x4){0.f, 0.f, 0.f, 0.f};

  for (int kt = 0; kt < K; kt += 32) {
#pragma unroll
    for (int i = 0; i < BM / 64; ++i)
      gload16(Aa + (long)i * 64 * lda + kt, &As[i * 2048 + tid * 8]);
#pragma unroll
    for (int i = 0; i < BN / 64; ++i)
      gload16(Ba + (long)i * 64 * ldb + kt, &Bs[i * 2048 + tid * 8]);
    __syncthreads();
    bfx8 afr[MI], bfr[NI];
#pragma unroll
    for (int i = 0; i < MI; ++i)
      afr[i] = *(const bfx8*)&As[(wm * WROWS + i * 16 + l15) * 32 + (lg << 3)];
#pragma unroll
    for (int j = 0; j < NI; ++j)
      bfr[j] = *(const bfx8*)&Bs[(wn * WCOLS + j * 16 + l15) * 32 + (lg << 3)];
#pragma unroll
    for (int i = 0; i < MI; ++i)
#pragma unroll
      for (int j = 0; j < NI; ++j)
        acc[i][j] = __builtin_amdgcn_mfma_f32_16x16x32_bf16(afr[i], bfr[j], acc[i][j], 0, 0, 0);
    __syncthreads();
  }

  const int gm0 = by * BM + wm * WROWS;
  const int gn0 = bx * BN + wn * WCOLS;
#pragma unroll
  for (int i = 0; i < MI; ++i) {
#pragma unroll
    for (int j = 0; j < NI; ++j) {
      const int gn = gn0 + j * 16 + l15;
      const float bv = (bias && z == 0) ? bias[gn] : 0.f;
#pragma unroll
      for (int r = 0; r < 4; ++r) {
        const int gm = gm0 + i * 16 + (lg << 2) + r;
        float v = acc[i][j][r] + bv;
        if (RELU) v = fmaxf(v, 0.f);
        if constexpr (EPI == 0) {
          ((float*)out)[z * sCz + (long)gm * ldc + gn] = v;
        } else if constexpr (EPI == 1) {
          ((u16*)out)[z * sCz + (long)gm * ldc + gn] = f2bf(v);
        } else if constexpr (EPI == 3) {
          const int b = gm / Ttok, t = gm - b * Ttok;
          const int hh = gn >> 6, dk = gn & 63;
          ((u16*)out)[(((long)(b * 16 + hh) * Ttok + t) << 6) + dk] = f2bf(v);
        }
      }
    }
  }
}

// ---------------- 256x256 8-phase GEMM (T2+T3+T4+T5) ----------------
#define MMAQ(hm, hn)                                                                   \
  {                                                                                    \
    _Pragma("unroll") for (int kk = 0; kk < 2; ++kk)                                   \
        _Pragma("unroll") for (int i = 0; i < 4; ++i)                                  \
            _Pragma("unroll") for (int jn = 0; jn < 2; ++jn)                           \
                acc[(hm)*4 + i][(hn)*2 + jn] = __builtin_amdgcn_mfma_f32_16x16x32_bf16( \
                    a[i][kk], b[jn][kk], acc[(hm)*4 + i][(hn)*2 + jn], 0, 0, 0);       \
  }

template <int EPI, bool RELU>
__global__ __launch_bounds__(512, 2) void gemm256(const u16* __restrict__ A, int lda,
                                                  const u16* __restrict__ Bt, int ldb,
                                                  const float* __restrict__ bias,
                                                  void* __restrict__ out, int ldc, int K,
                                                  int Ttok, void* __restrict__ out2,
                                                  void* __restrict__ out3, int gx) {
  __shared__ u16 lds[2][2][2][8192];  // [dbuf][A/B][half][128*64]
  const int tid = threadIdx.x, lane = tid & 63;
  const int wid = tid >> 6, wm = wid >> 2, wn = wid & 3;
  const int l15 = lane & 15, lg = lane >> 4;
  const int mt = blockIdx.x % gx;
  const int nt_ = blockIdx.x / gx;
  const int NT = K >> 6;

  const int r0 = tid >> 3;
  const int blkx = (tid & 7) ^ (r0 & 7);
  const u16* Abase = A + (long)(mt * 256 + r0) * lda + blkx * 8;
  const u16* Bbase = Bt + (long)(nt_ * 256 + r0) * ldb + blkx * 8;

  auto stageA = [&](int s, int half) {
    const int kts = (s < NT ? s : NT - 1) << 6;
    const u16* g = Abase + (long)(half * 128) * lda + kts;
    gload16(g, &lds[s & 1][0][half][tid * 8]);
    gload16(g + (long)64 * lda, &lds[s & 1][0][half][(512 + tid) * 8]);
  };
  auto stageB = [&](int s, int half) {
    const int kts = (s < NT ? s : NT - 1) << 6;
    const u16* g = Bbase + (long)(half * 128) * ldb + kts;
    gload16(g, &lds[s & 1][1][half][tid * 8]);
    gload16(g + (long)64 * ldb, &lds[s & 1][1][half][(512 + tid) * 8]);
  };

  f32x4 acc[8][4];
#pragma unroll
  for (int i = 0; i < 8; ++i)
#pragma unroll
    for (int j = 0; j < 4; ++j) acc[i][j] = (f32x4){0.f, 0.f, 0.f, 0.f};
  bfx8 a[4][2], b[2][2];

  const int sw = l15 & 7;
  auto loadA = [&](int buf, int hm) {
#pragma unroll
    for (int i = 0; i < 4; ++i) {
      const int row = hm * 64 + i * 16 + l15;
#pragma unroll
      for (int kk = 0; kk < 2; ++kk)
        a[i][kk] = *(const bfx8*)&lds[buf][0][wm][row * 64 + (((kk * 4 + lg) ^ sw) << 3)];
    }
  };
  auto loadB = [&](int buf, int hn) {
#pragma unroll
    for (int jn = 0; jn < 2; ++jn) {
      const int row = (wn & 1) * 64 + hn * 32 + jn * 16 + l15;
#pragma unroll
      for (int kk = 0; kk < 2; ++kk)
        b[jn][kk] = *(const bfx8*)&lds[buf][1][wn >> 1][row * 64 + (((kk * 4 + lg) ^ sw) << 3)];
    }
  };

  stageA(0, 0); stageA(0, 1); stageB(0, 0); stageB(0, 1);
  stageA(1, 0); stageA(1, 1);
  asm volatile("s_waitcnt vmcnt(4)" ::: "memory");
  __builtin_amdgcn_s_barrier();

  for (int t = 0; t < NT; ++t) {
    const int p = t & 1;
    loadA(p, 0); loadB(p, 0);
    stageB(t + 1, 0);
    __builtin_amdgcn_s_barrier();
    asm volatile("s_waitcnt lgkmcnt(0)" ::: "memory");
    __builtin_amdgcn_s_setprio(1);
    MMAQ(0, 0);
    __builtin_amdgcn_s_setprio(0);
    __builtin_amdgcn_s_barrier();
    loadB(p, 1);
    stageB(t + 1, 1);
    __builtin_amdgcn_s_barrier();
    asm volatile("s_waitcnt lgkmcnt(0)" ::: "memory");
    __builtin_amdgcn_s_setprio(1);
    MMAQ(0, 1);
    __builtin_amdgcn_s_setprio(0);
    __builtin_amdgcn_s_barrier();
    loadA(p, 1); loadB(p, 0);
    stageA(t + 2, 0);
    __builtin_amdgcn_s_barrier();
    asm volatile("s_waitcnt lgkmcnt(0)" ::: "memory");
    __builtin_amdgcn_s_setprio(1);
    MMAQ(1, 0);
    __builtin_amdgcn_s_setprio(0);
    __builtin_amdgcn_s_barrier();
    loadB(p, 1);
    stageA(t + 2, 1);
    asm volatile("s_waitcnt vmcnt(4)" ::: "memory");
    __builtin_amdgcn_s_barrier();
    asm volatile("s_waitcnt lgkmcnt(0)" ::: "memory");
    __builtin_amdgcn_s_setprio(1);
    MMAQ(1, 1);
    __builtin_amdgcn_s_setprio(0);
    __builtin_amdgcn_s_barrier();
  }

  const int gm0 = mt * 256 + wm * 128;
  const int gn0 = nt_ * 256 + wn * 64;
#pragma unroll
  for (int ii = 0; ii < 8; ++ii) {
#pragma unroll
    for (int jj = 0; jj < 4; ++jj) {
      const int gn = gn0 + jj * 16 + l15;
      const float bv = bias ? bias[gn] : 0.f;
#pragma unroll
      for (int r = 0; r < 4; ++r) {
        const int gm = gm0 + ii * 16 + (lg << 2) + r;
        float v = acc[ii][jj][r] + bv;
        if (RELU) v = fmaxf(v, 0.f);
        if constexpr (EPI == 0) {
          ((float*)out)[(long)gm * ldc + gn] = v;
        } else if constexpr (EPI == 1) {
          ((u16*)out)[(long)gm * ldc + gn] = f2bf(v);
        } else if constexpr (EPI == 6) {
          const int bq = gm / Ttok, t2 = gm - bq * Ttok;
          const int sec = gn >> 10, w1 = gn & 1023;
          const int hh = w1 >> 6, dk = w1 & 63;
          const u16 val = f2bf(v);
          if (sec == 0)
            ((u16*)out)[(((long)(bq * 16 + hh) * Ttok + t2) << 6) + dk] = val;
          else if (sec == 1)
            ((u16*)out2)[(((long)(bq * 16 + hh) * Ttok + t2) << 6) + dk] = val;
          else
            ((u16*)out3)[((long)((bq * 16 + hh) << 6) + dk) * Ttok + t2] = val;
        } else if constexpr (EPI == 7) {
          const int bq = gm / Ttok, t2 = gm - bq * Ttok;
          const int sec = gn >> 10, w1 = gn & 1023;
          const int hh = w1 >> 6, dk = w1 & 63;
          const u16 val = f2bf(v);
          if (sec == 0)
            ((u16*)out)[(((long)(bq * 16 + hh) * Ttok + t2) << 6) + dk] = val;
          else
            ((u16*)out2)[((long)((bq * 16 + hh) << 6) + dk) * Ttok + t2] = val;
        }
      }
    }
  }
}

// ---------------- driver ----------------
extern "C" void kernel_launch(void* const* d_in, const int* in_sizes, int n_in,
                              void* d_out, int out_size, void* d_ws, size_t ws_size,
                              hipStream_t stream) {
  const int* x = (const int*)d_in[0];
  const float* enc = (const float*)d_in[1];
  const float* emb = (const float*)d_in[2];
  const float* pe = (const float*)d_in[3];
  const float* a1w = (const float*)d_in[4];
  const float* a1b = (const float*)d_in[5];
  const float* a2w = (const float*)d_in[6];
  const float* a2b = (const float*)d_in[7];
  const float* nra = (const float*)d_in[8];
  const float* nrb = (const float*)d_in[9];
  const float* f1w = (const float*)d_in[10];
  const float* f1b = (const float*)d_in[11];
  const float* f2w = (const float*)d_in[12];
  const float* f2b = (const float*)d_in[13];
  const float* fcw = (const float*)d_in[14];
  const float* fcb = (const float*)d_in[15];
  float* out = (float*)d_out;

  char* base = (char*)d_ws;
  size_t off = 0;
  auto alloc = [&](size_t bytes) -> void* {
    void* p = base + off;
    off += (bytes + 255) & ~(size_t)255;
    return p;
  };
  const long wsz = 1024 * 1024;
  const bool big = ws_size >= (600ull << 20);
  u16* wT = (u16*)alloc(96ull * wsz * 2);    // all transposed weights: a1|a2|f1|f2
  u16* encb = (u16*)alloc(8ull * wsz * 2);   // encoder bf16 [8192,1024]
  float* h = (float*)alloc(4ull * wsz * 4);  // residual f32 [4096,1024]
  u16* hb = (u16*)alloc(4ull * wsz * 2);     // bf16 copy of h
  u16* qb = (u16*)alloc(4ull * wsz * 2);     // [B,H,512,64]
  u16* kb = (u16*)alloc(8ull * wsz * 2);     // [B,H,<=1024,64]
  u16* vtb = (u16*)alloc(8ull * wsz * 2);    // [B,H,64,<=1024]
  u16* ctxb = (u16*)alloc(4ull * wsz * 2);   // [4096,1024] bf16
  float* af = (float*)alloc(4ull * wsz * 4); // K-split partial 0
  float* af2 = (float*)alloc(4ull * wsz * 4);// K-split partial 1
  u16* midb = (u16*)alloc(16ull * wsz * 2);  // FFN mid bf16 [4096,4096]
  u16* fcT = qb;                             // fc^T (64 MB) aliases qb.. after layers
  u16* lgb = big ? (u16*)alloc(4096ull * 32000 * 2) : nullptr;  // bf16 logits

  u16* wTa1 = wT;               // [L][4][1024][1024]^T
  u16* wTa2 = wT + 24 * wsz;
  u16* wTf1 = wT + 48 * wsz;    // [L][4096][1024]
  u16* wTf2 = wT + 72 * wsz;    // [L][1024][4096]

  cvt_kernel<<<dim3(8192), dim3(256), 0, stream>>>(enc, encb, 8ll * wsz);
  embed_kernel<<<dim3(4096), dim3(256), 0, stream>>>(x, emb, pe, h, hb);
  wconv_kernel<<<dim3(32, 32, 24), dim3(256), 0, stream>>>(a1w, wTa1, 1024, 1024);
  wconv_kernel<<<dim3(32, 32, 24), dim3(256), 0, stream>>>(a2w, wTa2, 1024, 1024);
  wconv_kernel<<<dim3(128, 32, 6), dim3(256), 0, stream>>>(f1w, wTf1, 1024, 4096);
  wconv_kernel<<<dim3(32, 128, 6), dim3(256), 0, stream>>>(f2w, wTf2, 4096, 1024);

  for (int l = 0; l < 6; ++l) {
    const float* b1 = a1b + (long)l * 4096;
    const float* b2 = a2b + (long)l * 4096;
    const u16* w1 = wTa1 + (long)l * 4 * wsz;
    const u16* w2 = wTa2 + (long)l * 4 * wsz;

    // ---- self attention ----
    gemm256<6, false><<<dim3(192), dim3(512), 0, stream>>>(
        hb, 1024, w1, 1024, b1, qb, 0, 1024, 512, kb, vtb, 16);
    attn_kernel<512><<<dim3(8, 128), dim3(256), 0, stream>>>(qb, kb, vtb, ctxb);
    gemm_bt<128, 128, 2, 2, 0, false><<<dim3(8, 32, 2), dim3(256), 0, stream>>>(
        ctxb, 512, 1024, w1 + 3 * wsz, 512, 1024, b1 + 3072, af, 4194304, 1024, 512, 0);
    addnorm_kernel<<<dim3(4096), dim3(256), 0, stream>>>(
        af, af2, h, hb, nra + (l * 3 + 0) * 1024, nrb + (l * 3 + 0) * 1024);

    // ---- cross attention ----
    gemm_bt<128, 128, 2, 2, 3, false><<<dim3(8, 32, 1), dim3(256), 0, stream>>>(
        hb, 0, 1024, w2, 0, 1024, b2, qb, 0, 0, 1024, 512);
    gemm256<7, false><<<dim3(256), dim3(512), 0, stream>>>(
        encb, 1024, w2 + wsz, 1024, b2 + 1024, kb, 0, 1024, 1024, vtb, nullptr, 32);
    attn_kernel<1024><<<dim3(8, 128), dim3(256), 0, stream>>>(qb, kb, vtb, ctxb);
    gemm_bt<128, 128, 2, 2, 0, false><<<dim3(8, 32, 2), dim3(256), 0, stream>>>(
        ctxb, 512, 1024, w2 + 3 * wsz, 512, 1024, b2 + 3072, af, 4194304, 1024, 512, 0);
    addnorm_kernel<<<dim3(4096), dim3(256), 0, stream>>>(
        af, af2, h, hb, nra + (l * 3 + 1) * 1024, nrb + (l * 3 + 1) * 1024);

    // ---- ffn ----
    gemm256<1, true><<<dim3(256), dim3(512), 0, stream>>>(
        hb, 1024, wTf1 + (long)l * 4 * wsz, 1024, f1b + (long)l * 4096, midb, 4096, 1024, 0,
        nullptr, nullptr, 16);
    gemm_bt<128, 128, 2, 2, 0, false><<<dim3(8, 32, 2), dim3(256), 0, stream>>>(
        midb, 2048, 4096, wTf2 + (long)l * 4 * wsz, 2048, 4096, f2b + (long)l * 1024, af,
        4194304, 1024, 2048, 0);
    addnorm_kernel<<<dim3(4096), dim3(256), 0, stream>>>(
        af, af2, h, hb, nra + (l * 3 + 2) * 1024, nrb + (l * 3 + 2) * 1024);
  }

  // final projection + log_softmax
  wconv_kernel<<<dim3(1000, 32, 1), dim3(256), 0, stream>>>(fcw, fcT, 1024, 32000);
  if (big) {
    gemm256<1, false><<<dim3(2000), dim3(512), 0, stream>>>(
        hb, 1024, fcT, 1024, fcb, lgb, 32000, 1024, 0, nullptr, nullptr, 16);
    logsoftmax_bf16_kernel<<<dim3(4096), dim3(512), 0, stream>>>(lgb, out);
  } else {
    gemm256<0, false><<<dim3(2000), dim3(512), 0, stream>>>(
        hb, 1024, fcT, 1024, fcb, out, 32000, 1024, 0, nullptr, nullptr, 16);
    logsoftmax_kernel<<<dim3(4096), dim3(256), 0, stream>>>(out);
  }
}

// Round 10
// 3087.551 us; speedup vs baseline: 1.2503x; 1.0703x over previous
//
#include <hip/hip_runtime.h>

typedef __attribute__((ext_vector_type(4))) float f32x4;
typedef __attribute__((ext_vector_type(8))) __bf16 bfx8;
typedef unsigned short u16;
typedef unsigned int u32;

// ---------------- helpers ----------------
__device__ __forceinline__ u16 f2bf(float f) {
  u32 u = __builtin_bit_cast(u32, f);
  u = (u + 0x7FFFu + ((u >> 16) & 1u)) >> 16;
  return (u16)u;
}
__device__ __forceinline__ float bf2f(u16 u) {
  return __builtin_bit_cast(float, ((u32)u) << 16);
}

typedef __attribute__((address_space(1))) const void gvoid;
typedef __attribute__((address_space(3))) void svoid;
__device__ __forceinline__ void gload16(const void* g, void* l) {
  __builtin_amdgcn_global_load_lds((gvoid*)g, (svoid*)l, 16, 0, 0);
}

__device__ __forceinline__ float wredsum(float v) {
#pragma unroll
  for (int o = 32; o; o >>= 1) v += __shfl_xor(v, o, 64);
  return v;
}
__device__ __forceinline__ float wredmax(float v) {
#pragma unroll
  for (int o = 32; o; o >>= 1) v = fmaxf(v, __shfl_xor(v, o, 64));
  return v;
}

// ---------------- small kernels ----------------
// fp32 [z][K][N] -> bf16 [z][N][K]
__global__ __launch_bounds__(256) void wconv_kernel(const float* __restrict__ in,
                                                    u16* __restrict__ out, int K, int N) {
  __shared__ u16 tile[32][33];
  const long z = blockIdx.z;
  const float* iz = in + z * (long)K * N;
  u16* oz = out + z * (long)K * N;
  const int n0 = blockIdx.x << 5, k0 = blockIdx.y << 5;
  const int tx = threadIdx.x & 31, ty = threadIdx.x >> 5;
#pragma unroll
  for (int i = 0; i < 4; ++i)
    tile[ty + 8 * i][tx] = f2bf(iz[(long)(k0 + ty + 8 * i) * N + n0 + tx]);
  __syncthreads();
#pragma unroll
  for (int i = 0; i < 4; ++i)
    oz[(long)(n0 + ty + 8 * i) * K + k0 + tx] = tile[tx][ty + 8 * i];
}

__global__ __launch_bounds__(256) void cvt_kernel(const float* __restrict__ in,
                                                  u16* __restrict__ out, long n) {
  long i = ((long)blockIdx.x * 256 + threadIdx.x) * 4;
  if (i + 3 < n) {
    float4 v = *(const float4*)(in + i);
    ushort4 o = {f2bf(v.x), f2bf(v.y), f2bf(v.z), f2bf(v.w)};
    *(ushort4*)(out + i) = o;
  }
}

__global__ __launch_bounds__(256) void embed_kernel(const int* __restrict__ x,
                                                    const float* __restrict__ emb,
                                                    const float* __restrict__ pe,
                                                    float* __restrict__ h,
                                                    u16* __restrict__ hb) {
  const int row = blockIdx.x;
  const int b = row >> 9, t = row & 511;
  const long tok = (long)x[b * 513 + t];
  const int d = threadIdx.x << 2;
  float4 e = *(const float4*)(emb + tok * 1024 + d);
  float4 p = *(const float4*)(pe + (long)t * 1024 + d);
  float4 v = {e.x + p.x, e.y + p.y, e.z + p.z, e.w + p.w};
  *(float4*)(h + (long)row * 1024 + d) = v;
  ushort4 o = {f2bf(v.x), f2bf(v.y), f2bf(v.z), f2bf(v.w)};
  *(ushort4*)(hb + (long)row * 1024 + d) = o;
}

// h = norm(h + delta + delta2); single-pass dual reduction
__global__ __launch_bounds__(256) void addnorm_kernel(const float* __restrict__ delta,
                                                      const float* __restrict__ delta2,
                                                      float* __restrict__ h,
                                                      u16* __restrict__ hb,
                                                      const float* __restrict__ ga,
                                                      const float* __restrict__ gb) {
  __shared__ float r1[4], r2[4];
  const long row = blockIdx.x;
  const int d = threadIdx.x << 2;
  float4 a = *(const float4*)(h + row * 1024 + d);
  float4 q = *(const float4*)(delta + row * 1024 + d);
  float4 q2 = *(const float4*)(delta2 + row * 1024 + d);
  float x0 = a.x + q.x + q2.x, x1 = a.y + q.y + q2.y;
  float x2 = a.z + q.z + q2.z, x3 = a.w + q.w + q2.w;
  float s1 = wredsum(x0 + x1 + x2 + x3);
  float s2 = wredsum(x0 * x0 + x1 * x1 + x2 * x2 + x3 * x3);
  if ((threadIdx.x & 63) == 0) { r1[threadIdx.x >> 6] = s1; r2[threadIdx.x >> 6] = s2; }
  __syncthreads();
  float S1 = r1[0] + r1[1] + r1[2] + r1[3];
  float S2 = r2[0] + r2[1] + r2[2] + r2[3];
  float mu = S1 * (1.0f / 1024.0f);
  float var = (S2 - S1 * mu) * (1.0f / 1023.0f);
  float inv = 1.0f / (sqrtf(fmaxf(var, 0.f)) + 1e-6f);
  float4 g4 = *(const float4*)(ga + d);
  float4 b4 = *(const float4*)(gb + d);
  float y0 = g4.x * (x0 - mu) * inv + b4.x;
  float y1 = g4.y * (x1 - mu) * inv + b4.y;
  float y2 = g4.z * (x2 - mu) * inv + b4.z;
  float y3 = g4.w * (x3 - mu) * inv + b4.w;
  float4 y = {y0, y1, y2, y3};
  *(float4*)(h + row * 1024 + d) = y;
  ushort4 o = {f2bf(y0), f2bf(y1), f2bf(y2), f2bf(y3)};
  *(ushort4*)(hb + row * 1024 + d) = o;
}

// in-place log_softmax over rows of 32000 fp32 (fallback)
__global__ __launch_bounds__(256) void logsoftmax_kernel(float* __restrict__ lg) {
  const long row = blockIdx.x;
  float* lr = lg + row * 32000L;
  float m = -1e30f, s = 0.f;
  for (int j = threadIdx.x; j < 8000; j += 256) {
    float4 v = *(const float4*)(lr + (long)j * 4);
    float lm = fmaxf(fmaxf(v.x, v.y), fmaxf(v.z, v.w));
    if (lm > m) { s *= __expf(m - lm); m = lm; }
    s += __expf(v.x - m) + __expf(v.y - m) + __expf(v.z - m) + __expf(v.w - m);
  }
#pragma unroll
  for (int o = 32; o; o >>= 1) {
    float om = __shfl_xor(m, o, 64), os = __shfl_xor(s, o, 64);
    float M = fmaxf(m, om);
    s = s * __expf(m - M) + os * __expf(om - M);
    m = M;
  }
  __shared__ float rm[4], rs[4];
  if ((threadIdx.x & 63) == 0) { rm[threadIdx.x >> 6] = m; rs[threadIdx.x >> 6] = s; }
  __syncthreads();
  float M = fmaxf(fmaxf(rm[0], rm[1]), fmaxf(rm[2], rm[3]));
  float S = rs[0] * __expf(rm[0] - M) + rs[1] * __expf(rm[1] - M) +
            rs[2] * __expf(rm[2] - M) + rs[3] * __expf(rm[3] - M);
  float lse = M + __logf(S);
  for (int j = threadIdx.x; j < 8000; j += 256) {
    float4 v = *(const float4*)(lr + (long)j * 4);
    v.x -= lse; v.y -= lse; v.z -= lse; v.w -= lse;
    *(float4*)(lr + (long)j * 4) = v;
  }
}

// LDS-cached log_softmax from bf16 logits -> f32 out.
__global__ __launch_bounds__(512) void logsoftmax_bf16_kernel(const u16* __restrict__ lg,
                                                              float* __restrict__ out) {
  __shared__ u16 rl[32000];
  __shared__ float rr[8];
  const long row = blockIdx.x;
  const u16* lr = lg + row * 32000L;
  float* od = out + row * 32000L;
  const int tid = threadIdx.x;
  float m0 = -1e30f, m1 = -1e30f;
  for (int j = tid * 8; j < 32000; j += 4096) {
    ushort4 a = *(const ushort4*)(lr + j);
    ushort4 b = *(const ushort4*)(lr + j + 4);
    *(ushort4*)&rl[j] = a;
    *(ushort4*)&rl[j + 4] = b;
    m0 = fmaxf(m0, fmaxf(fmaxf(bf2f(a.x), bf2f(a.y)), fmaxf(bf2f(a.z), bf2f(a.w))));
    m1 = fmaxf(m1, fmaxf(fmaxf(bf2f(b.x), bf2f(b.y)), fmaxf(bf2f(b.z), bf2f(b.w))));
  }
  float m = wredmax(fmaxf(m0, m1));
  if ((tid & 63) == 0) rr[tid >> 6] = m;
  __syncthreads();
  m = fmaxf(fmaxf(fmaxf(rr[0], rr[1]), fmaxf(rr[2], rr[3])),
            fmaxf(fmaxf(rr[4], rr[5]), fmaxf(rr[6], rr[7])));
  __syncthreads();
  float s0 = 0.f, s1 = 0.f;
  for (int j = tid * 8; j < 32000; j += 4096) {
    ushort4 a = *(const ushort4*)&rl[j];
    ushort4 b = *(const ushort4*)&rl[j + 4];
    s0 += __expf(bf2f(a.x) - m) + __expf(bf2f(a.y) - m) +
          __expf(bf2f(a.z) - m) + __expf(bf2f(a.w) - m);
    s1 += __expf(bf2f(b.x) - m) + __expf(bf2f(b.y) - m) +
          __expf(bf2f(b.z) - m) + __expf(bf2f(b.w) - m);
  }
  float s = wredsum(s0 + s1);
  if ((tid & 63) == 0) rr[tid >> 6] = s;
  __syncthreads();
  s = rr[0] + rr[1] + rr[2] + rr[3] + rr[4] + rr[5] + rr[6] + rr[7];
  const float lse = m + __logf(s);
  for (int j = tid * 8; j < 32000; j += 4096) {
    ushort4 a = *(const ushort4*)&rl[j];
    ushort4 b = *(const ushort4*)&rl[j + 4];
    float4 o0 = {bf2f(a.x) - lse, bf2f(a.y) - lse, bf2f(a.z) - lse, bf2f(a.w) - lse};
    float4 o1 = {bf2f(b.x) - lse, bf2f(b.y) - lse, bf2f(b.z) - lse, bf2f(b.w) - lse};
    *(float4*)(od + j) = o0;
    *(float4*)(od + j + 4) = o1;
  }
}

// ---------------- fused flash attention (8-wave, LDS-staged, double-buffered) ----------------
// 512 threads = 8 waves x 16 q-rows (block covers 128 q-rows). K/V tiles shared by
// all 8 waves (staging per q-row halved vs 4-wave); 24 waves/CU at 3 blocks/CU.
template <int SKV>
__global__ __launch_bounds__(512) void attn_kernel(const u16* __restrict__ Q,
                                                   const u16* __restrict__ Kb,
                                                   const u16* __restrict__ Vt,
                                                   u16* __restrict__ ctx) {
  __shared__ u16 Kl[2][4096];    // [buf][64 kv][64 dk], chunk-XOR-swizzled
  __shared__ u16 Vl[2][4096];    // [buf][64 dk][64 kv]
  __shared__ u16 Pl[8][16][72];  // per-wave P: [q][kv]
  const int tid = threadIdx.x, lane = tid & 63, wave = tid >> 6;
  const int l15 = lane & 15, lg = lane >> 4;
  const int bh = blockIdx.y;
  const int qrow = blockIdx.x * 128 + wave * 16 + l15;
  const u16* qp = Q + ((long)bh * 512 + qrow) * 64 + lg * 8;
  bfx8 qf0 = *(const bfx8*)(qp);
  bfx8 qf1 = *(const bfx8*)(qp + 32);

  const int srow = tid >> 3;                  // 0..63
  const int schunk = (tid & 7) ^ (srow & 7);  // pre-swizzled global chunk
  const u16* Kbb = Kb + ((long)bh * SKV + srow) * 64 + schunk * 8;
  const u16* Vtb2 = Vt + ((long)bh * 64 + srow) * SKV + schunk * 8;

  auto stage = [&](int t, int buf) {
    const int kv0 = t * 64;
    gload16(Kbb + (long)kv0 * 64, &Kl[buf][tid * 8]);
    gload16(Vtb2 + kv0, &Vl[buf][tid * 8]);
  };

  const f32x4 zf = {0.f, 0.f, 0.f, 0.f};
  f32x4 acc_o[4] = {zf, zf, zf, zf};
  float mrun = -1e30f, lrun = 0.f;
  const int swk = l15 & 7;
  constexpr int NT = SKV / 64;

  stage(0, 0);
  __syncthreads();
  int buf = 0;
#pragma unroll 1
  for (int t = 0; t < NT; ++t) {
    if (t + 1 < NT) stage(t + 1, buf ^ 1);  // overlaps with compute below
    // S^T tile: lane holds S[q=l15][kv=kvt*16+lg*4+r]
    f32x4 sacc[4];
#pragma unroll
    for (int kvt = 0; kvt < 4; ++kvt) {
      const int krow = kvt * 16 + l15;
      bfx8 kf0 = *(const bfx8*)&Kl[buf][krow * 64 + ((lg ^ swk) << 3)];
      bfx8 kf1 = *(const bfx8*)&Kl[buf][krow * 64 + (((4 + lg) ^ swk) << 3)];
      f32x4 tt = __builtin_amdgcn_mfma_f32_16x16x32_bf16(kf0, qf0, zf, 0, 0, 0);
      sacc[kvt] = __builtin_amdgcn_mfma_f32_16x16x32_bf16(kf1, qf1, tt, 0, 0, 0);
    }
    // online softmax (q = l15; reduce over lg groups)
    float pm = -1e30f;
#pragma unroll
    for (int kvt = 0; kvt < 4; ++kvt)
#pragma unroll
      for (int r = 0; r < 4; ++r) pm = fmaxf(pm, sacc[kvt][r]);
    pm = fmaxf(pm, __shfl_xor(pm, 16, 64));
    pm = fmaxf(pm, __shfl_xor(pm, 32, 64));
    pm *= 0.125f;
    const bool grow = !__all(pm <= mrun);  // exact defer: skip rescale if max unchanged
    const float mnew = grow ? fmaxf(mrun, pm) : mrun;
    float psum = 0.f;
#pragma unroll
    for (int kvt = 0; kvt < 4; ++kvt)
#pragma unroll
      for (int r = 0; r < 4; ++r) {
        float p = __expf(sacc[kvt][r] * 0.125f - mnew);
        psum += p;
        Pl[wave][l15][kvt * 16 + lg * 4 + r] = f2bf(p);
      }
    psum += __shfl_xor(psum, 16, 64);
    psum += __shfl_xor(psum, 32, 64);
    if (grow) {
      const float corr = __expf(mrun - mnew);
      lrun = lrun * corr + psum;
      mrun = mnew;
#pragma unroll
      for (int dt = 0; dt < 4; ++dt) {
        acc_o[dt][0] *= corr; acc_o[dt][1] *= corr;
        acc_o[dt][2] *= corr; acc_o[dt][3] *= corr;
      }
    } else {
      lrun += psum;
    }
    // O^T += V^T-frag x P-frag
    bfx8 pf0 = *(const bfx8*)&Pl[wave][l15][lg * 8];
    bfx8 pf1 = *(const bfx8*)&Pl[wave][l15][32 + lg * 8];
#pragma unroll
    for (int dt = 0; dt < 4; ++dt) {
      const int vrow = dt * 16 + l15;
      bfx8 vf0 = *(const bfx8*)&Vl[buf][vrow * 64 + ((lg ^ swk) << 3)];
      bfx8 vf1 = *(const bfx8*)&Vl[buf][vrow * 64 + (((4 + lg) ^ swk) << 3)];
      acc_o[dt] = __builtin_amdgcn_mfma_f32_16x16x32_bf16(vf0, pf0, acc_o[dt], 0, 0, 0);
      acc_o[dt] = __builtin_amdgcn_mfma_f32_16x16x32_bf16(vf1, pf1, acc_o[dt], 0, 0, 0);
    }
    __syncthreads();  // drains staging vmcnt + ensures buf reads done before overwrite
    buf ^= 1;
  }
  const float inv = 1.0f / lrun;
  const int b = bh >> 4, hh = bh & 15;
  u16* crow = ctx + ((long)b * 512 + qrow) * 1024 + hh * 64;
#pragma unroll
  for (int dt = 0; dt < 4; ++dt)
#pragma unroll
    for (int r = 0; r < 4; ++r)
      crow[dt * 16 + lg * 4 + r] = f2bf(acc_o[dt][r] * inv);
}

// ---------------- 128-class GEMM (2-barrier, m97 structure) ----------------
// z = K-split index; bias only for z==0. EPI: 0=f32 rm, 1=bf16 rm, 3=bf16 [b,h,t,dk]
template <int BM, int BN, int WMW, int WNW, int EPI, bool RELU>
__global__ __launch_bounds__(256) void gemm_bt(const u16* __restrict__ A, long sAz, int lda,
                                               const u16* __restrict__ Bt, long sBz, int ldb,
                                               const float* __restrict__ bias,
                                               void* __restrict__ out, long sCz, int ldc,
                                               int K, int Ttok) {
  constexpr int WROWS = BM / WMW, WCOLS = BN / WNW;
  constexpr int MI = WROWS / 16, NI = WCOLS / 16;
  __shared__ u16 As[BM * 32];
  __shared__ u16 Bs[BN * 32];
  const int tid = threadIdx.x, lane = tid & 63, wave = tid >> 6;
  const int l15 = lane & 15, lg = lane >> 4;
  const int wm = wave / WNW, wn = wave % WNW;
  const int bx = blockIdx.x, by = blockIdx.y;
  const long z = blockIdx.z;
  const int srow = tid >> 2, scol = (tid & 3) << 3;
  const u16* Aa = A + z * sAz + (long)(by * BM + srow) * lda + scol;
  const u16* Ba = Bt + z * sBz + (long)(bx * BN + srow) * ldb + scol;

  f32x4 acc[MI][NI];
#pragma unroll
  for (int i = 0; i < MI; ++i)
#pragma unroll
    for (int j = 0; j < NI; ++j) acc[i][j] = (f32x4){0.f, 0.f, 0.f, 0.f};

  for (int kt = 0; kt < K; kt += 32) {
#pragma unroll
    for (int i = 0; i < BM / 64; ++i)
      gload16(Aa + (long)i * 64 * lda + kt, &As[i * 2048 + tid * 8]);
#pragma unroll
    for (int i = 0; i < BN / 64; ++i)
      gload16(Ba + (long)i * 64 * ldb + kt, &Bs[i * 2048 + tid * 8]);
    __syncthreads();
    bfx8 afr[MI], bfr[NI];
#pragma unroll
    for (int i = 0; i < MI; ++i)
      afr[i] = *(const bfx8*)&As[(wm * WROWS + i * 16 + l15) * 32 + (lg << 3)];
#pragma unroll
    for (int j = 0; j < NI; ++j)
      bfr[j] = *(const bfx8*)&Bs[(wn * WCOLS + j * 16 + l15) * 32 + (lg << 3)];
#pragma unroll
    for (int i = 0; i < MI; ++i)
#pragma unroll
      for (int j = 0; j < NI; ++j)
        acc[i][j] = __builtin_amdgcn_mfma_f32_16x16x32_bf16(afr[i], bfr[j], acc[i][j], 0, 0, 0);
    __syncthreads();
  }

  const int gm0 = by * BM + wm * WROWS;
  const int gn0 = bx * BN + wn * WCOLS;
#pragma unroll
  for (int i = 0; i < MI; ++i) {
#pragma unroll
    for (int j = 0; j < NI; ++j) {
      const int gn = gn0 + j * 16 + l15;
      const float bv = (bias && z == 0) ? bias[gn] : 0.f;
#pragma unroll
      for (int r = 0; r < 4; ++r) {
        const int gm = gm0 + i * 16 + (lg << 2) + r;
        float v = acc[i][j][r] + bv;
        if (RELU) v = fmaxf(v, 0.f);
        if constexpr (EPI == 0) {
          ((float*)out)[z * sCz + (long)gm * ldc + gn] = v;
        } else if constexpr (EPI == 1) {
          ((u16*)out)[z * sCz + (long)gm * ldc + gn] = f2bf(v);
        } else if constexpr (EPI == 3) {
          const int b = gm / Ttok, t = gm - b * Ttok;
          const int hh = gn >> 6, dk = gn & 63;
          ((u16*)out)[(((long)(b * 16 + hh) * Ttok + t) << 6) + dk] = f2bf(v);
        }
      }
    }
  }
}

// ---------------- 256x256 8-phase GEMM (T2+T3+T4+T5) ----------------
// L2-aware XCD chunking (round-5 best config): per XCD S=gx/8 mt-rows x full nt sweep.
#define MMAQ(hm, hn)                                                                   \
  {                                                                                    \
    _Pragma("unroll") for (int kk = 0; kk < 2; ++kk)                                   \
        _Pragma("unroll") for (int i = 0; i < 4; ++i)                                  \
            _Pragma("unroll") for (int jn = 0; jn < 2; ++jn)                           \
                acc[(hm)*4 + i][(hn)*2 + jn] = __builtin_amdgcn_mfma_f32_16x16x32_bf16( \
                    a[i][kk], b[jn][kk], acc[(hm)*4 + i][(hn)*2 + jn], 0, 0, 0);       \
  }

template <int EPI, bool RELU>
__global__ __launch_bounds__(512, 2) void gemm256(const u16* __restrict__ A, int lda,
                                                  const u16* __restrict__ Bt, int ldb,
                                                  const float* __restrict__ bias,
                                                  void* __restrict__ out, int ldc, int K,
                                                  int Ttok, void* __restrict__ out2,
                                                  void* __restrict__ out3, int gx) {
  __shared__ u16 lds[2][2][2][8192];  // [dbuf][A/B][half][128*64]
  const int tid = threadIdx.x, lane = tid & 63;
  const int wid = tid >> 6, wm = wid >> 2, wn = wid & 3;
  const int l15 = lane & 15, lg = lane >> 4;
  const int S = gx >> 3;  // mt-rows per XCD (gx % 8 == 0)
  const int xcd = blockIdx.x & 7, idx = blockIdx.x >> 3;
  const int mt = xcd * S + idx % S;
  const int nt_ = idx / S;
  const int NT = K >> 6;

  const int r0 = tid >> 3;
  const int blkx = (tid & 7) ^ (r0 & 7);
  const u16* Abase = A + (long)(mt * 256 + r0) * lda + blkx * 8;
  const u16* Bbase = Bt + (long)(nt_ * 256 + r0) * ldb + blkx * 8;

  auto stageA = [&](int s, int half) {
    const int kts = (s < NT ? s : NT - 1) << 6;
    const u16* g = Abase + (long)(half * 128) * lda + kts;
    gload16(g, &lds[s & 1][0][half][tid * 8]);
    gload16(g + (long)64 * lda, &lds[s & 1][0][half][(512 + tid) * 8]);
  };
  auto stageB = [&](int s, int half) {
    const int kts = (s < NT ? s : NT - 1) << 6;
    const u16* g = Bbase + (long)(half * 128) * ldb + kts;
    gload16(g, &lds[s & 1][1][half][tid * 8]);
    gload16(g + (long)64 * ldb, &lds[s & 1][1][half][(512 + tid) * 8]);
  };

  f32x4 acc[8][4];
#pragma unroll
  for (int i = 0; i < 8; ++i)
#pragma unroll
    for (int j = 0; j < 4; ++j) acc[i][j] = (f32x4){0.f, 0.f, 0.f, 0.f};
  bfx8 a[4][2], b[2][2];

  const int sw = l15 & 7;
  auto loadA = [&](int buf, int hm) {
#pragma unroll
    for (int i = 0; i < 4; ++i) {
      const int row = hm * 64 + i * 16 + l15;
#pragma unroll
      for (int kk = 0; kk < 2; ++kk)
        a[i][kk] = *(const bfx8*)&lds[buf][0][wm][row * 64 + (((kk * 4 + lg) ^ sw) << 3)];
    }
  };
  auto loadB = [&](int buf, int hn) {
#pragma unroll
    for (int jn = 0; jn < 2; ++jn) {
      const int row = (wn & 1) * 64 + hn * 32 + jn * 16 + l15;
#pragma unroll
      for (int kk = 0; kk < 2; ++kk)
        b[jn][kk] = *(const bfx8*)&lds[buf][1][wn >> 1][row * 64 + (((kk * 4 + lg) ^ sw) << 3)];
    }
  };

  stageA(0, 0); stageA(0, 1); stageB(0, 0); stageB(0, 1);
  stageA(1, 0); stageA(1, 1);
  asm volatile("s_waitcnt vmcnt(4)" ::: "memory");
  __builtin_amdgcn_s_barrier();

  for (int t = 0; t < NT; ++t) {
    const int p = t & 1;
    loadA(p, 0); loadB(p, 0);
    stageB(t + 1, 0);
    __builtin_amdgcn_s_barrier();
    asm volatile("s_waitcnt lgkmcnt(0)" ::: "memory");
    __builtin_amdgcn_s_setprio(1);
    MMAQ(0, 0);
    __builtin_amdgcn_s_setprio(0);
    __builtin_amdgcn_s_barrier();
    loadB(p, 1);
    stageB(t + 1, 1);
    __builtin_amdgcn_s_barrier();
    asm volatile("s_waitcnt lgkmcnt(0)" ::: "memory");
    __builtin_amdgcn_s_setprio(1);
    MMAQ(0, 1);
    __builtin_amdgcn_s_setprio(0);
    __builtin_amdgcn_s_barrier();
    loadA(p, 1); loadB(p, 0);
    stageA(t + 2, 0);
    __builtin_amdgcn_s_barrier();
    asm volatile("s_waitcnt lgkmcnt(0)" ::: "memory");
    __builtin_amdgcn_s_setprio(1);
    MMAQ(1, 0);
    __builtin_amdgcn_s_setprio(0);
    __builtin_amdgcn_s_barrier();
    loadB(p, 1);
    stageA(t + 2, 1);
    asm volatile("s_waitcnt vmcnt(4)" ::: "memory");
    __builtin_amdgcn_s_barrier();
    asm volatile("s_waitcnt lgkmcnt(0)" ::: "memory");
    __builtin_amdgcn_s_setprio(1);
    MMAQ(1, 1);
    __builtin_amdgcn_s_setprio(0);
    __builtin_amdgcn_s_barrier();
  }

  const int gm0 = mt * 256 + wm * 128;
  const int gn0 = nt_ * 256 + wn * 64;
#pragma unroll
  for (int ii = 0; ii < 8; ++ii) {
#pragma unroll
    for (int jj = 0; jj < 4; ++jj) {
      const int gn = gn0 + jj * 16 + l15;
      const float bv = bias ? bias[gn] : 0.f;
#pragma unroll
      for (int r = 0; r < 4; ++r) {
        const int gm = gm0 + ii * 16 + (lg << 2) + r;
        float v = acc[ii][jj][r] + bv;
        if (RELU) v = fmaxf(v, 0.f);
        if constexpr (EPI == 0) {
          ((float*)out)[(long)gm * ldc + gn] = v;
        } else if constexpr (EPI == 1) {
          ((u16*)out)[(long)gm * ldc + gn] = f2bf(v);
        } else if constexpr (EPI == 6) {
          const int bq = gm / Ttok, t2 = gm - bq * Ttok;
          const int sec = gn >> 10, w1 = gn & 1023;
          const int hh = w1 >> 6, dk = w1 & 63;
          const u16 val = f2bf(v);
          if (sec == 0)
            ((u16*)out)[(((long)(bq * 16 + hh) * Ttok + t2) << 6) + dk] = val;
          else if (sec == 1)
            ((u16*)out2)[(((long)(bq * 16 + hh) * Ttok + t2) << 6) + dk] = val;
          else
            ((u16*)out3)[((long)((bq * 16 + hh) << 6) + dk) * Ttok + t2] = val;
        } else if constexpr (EPI == 7) {
          const int bq = gm / Ttok, t2 = gm - bq * Ttok;
          const int sec = gn >> 10, w1 = gn & 1023;
          const int hh = w1 >> 6, dk = w1 & 63;
          const u16 val = f2bf(v);
          if (sec == 0)
            ((u16*)out)[(((long)(bq * 16 + hh) * Ttok + t2) << 6) + dk] = val;
          else
            ((u16*)out2)[((long)((bq * 16 + hh) << 6) + dk) * Ttok + t2] = val;
        }
      }
    }
  }
}

// ---------------- driver ----------------
extern "C" void kernel_launch(void* const* d_in, const int* in_sizes, int n_in,
                              void* d_out, int out_size, void* d_ws, size_t ws_size,
                              hipStream_t stream) {
  const int* x = (const int*)d_in[0];
  const float* enc = (const float*)d_in[1];
  const float* emb = (const float*)d_in[2];
  const float* pe = (const float*)d_in[3];
  const float* a1w = (const float*)d_in[4];
  const float* a1b = (const float*)d_in[5];
  const float* a2w = (const float*)d_in[6];
  const float* a2b = (const float*)d_in[7];
  const float* nra = (const float*)d_in[8];
  const float* nrb = (const float*)d_in[9];
  const float* f1w = (const float*)d_in[10];
  const float* f1b = (const float*)d_in[11];
  const float* f2w = (const float*)d_in[12];
  const float* f2b = (const float*)d_in[13];
  const float* fcw = (const float*)d_in[14];
  const float* fcb = (const float*)d_in[15];
  float* out = (float*)d_out;

  char* base = (char*)d_ws;
  size_t off = 0;
  auto alloc = [&](size_t bytes) -> void* {
    void* p = base + off;
    off += (bytes + 255) & ~(size_t)255;
    return p;
  };
  const long wsz = 1024 * 1024;
  const bool big = ws_size >= (600ull << 20);
  u16* wT = (u16*)alloc(96ull * wsz * 2);    // all transposed weights: a1|a2|f1|f2
  u16* encb = (u16*)alloc(8ull * wsz * 2);   // encoder bf16 [8192,1024]
  float* h = (float*)alloc(4ull * wsz * 4);  // residual f32 [4096,1024]
  u16* hb = (u16*)alloc(4ull * wsz * 2);     // bf16 copy of h
  u16* qb = (u16*)alloc(4ull * wsz * 2);     // [B,H,512,64]
  u16* kb = (u16*)alloc(8ull * wsz * 2);     // [B,H,<=1024,64]
  u16* vtb = (u16*)alloc(8ull * wsz * 2);    // [B,H,64,<=1024]
  u16* ctxb = (u16*)alloc(4ull * wsz * 2);   // [4096,1024] bf16
  float* af = (float*)alloc(4ull * wsz * 4); // K-split partial 0
  float* af2 = (float*)alloc(4ull * wsz * 4);// K-split partial 1
  u16* midb = (u16*)alloc(16ull * wsz * 2);  // FFN mid bf16 [4096,4096]
  u16* fcT = qb;                             // fc^T (64 MB) aliases qb.. after layers
  u16* lgb = big ? (u16*)alloc(4096ull * 32000 * 2) : nullptr;  // bf16 logits

  u16* wTa1 = wT;               // [L][4][1024][1024]^T
  u16* wTa2 = wT + 24 * wsz;
  u16* wTf1 = wT + 48 * wsz;    // [L][4096][1024]
  u16* wTf2 = wT + 72 * wsz;    // [L][1024][4096]

  cvt_kernel<<<dim3(8192), dim3(256), 0, stream>>>(enc, encb, 8ll * wsz);
  embed_kernel<<<dim3(4096), dim3(256), 0, stream>>>(x, emb, pe, h, hb);
  wconv_kernel<<<dim3(32, 32, 24), dim3(256), 0, stream>>>(a1w, wTa1, 1024, 1024);
  wconv_kernel<<<dim3(32, 32, 24), dim3(256), 0, stream>>>(a2w, wTa2, 1024, 1024);
  wconv_kernel<<<dim3(128, 32, 6), dim3(256), 0, stream>>>(f1w, wTf1, 1024, 4096);
  wconv_kernel<<<dim3(32, 128, 6), dim3(256), 0, stream>>>(f2w, wTf2, 4096, 1024);

  for (int l = 0; l < 6; ++l) {
    const float* b1 = a1b + (long)l * 4096;
    const float* b2 = a2b + (long)l * 4096;
    const u16* w1 = wTa1 + (long)l * 4 * wsz;
    const u16* w2 = wTa2 + (long)l * 4 * wsz;

    // ---- self attention ----
    gemm256<6, false><<<dim3(192), dim3(512), 0, stream>>>(
        hb, 1024, w1, 1024, b1, qb, 0, 1024, 512, kb, vtb, 16);
    attn_kernel<512><<<dim3(4, 128), dim3(512), 0, stream>>>(qb, kb, vtb, ctxb);
    gemm_bt<128, 128, 2, 2, 0, false><<<dim3(8, 32, 2), dim3(256), 0, stream>>>(
        ctxb, 512, 1024, w1 + 3 * wsz, 512, 1024, b1 + 3072, af, 4194304, 1024, 512, 0);
    addnorm_kernel<<<dim3(4096), dim3(256), 0, stream>>>(
        af, af2, h, hb, nra + (l * 3 + 0) * 1024, nrb + (l * 3 + 0) * 1024);

    // ---- cross attention ----
    gemm_bt<64, 128, 2, 2, 3, false><<<dim3(8, 64, 1), dim3(256), 0, stream>>>(
        hb, 0, 1024, w2, 0, 1024, b2, qb, 0, 0, 1024, 512);
    gemm256<7, false><<<dim3(256), dim3(512), 0, stream>>>(
        encb, 1024, w2 + wsz, 1024, b2 + 1024, kb, 0, 1024, 1024, vtb, nullptr, 32);
    attn_kernel<1024><<<dim3(4, 128), dim3(512), 0, stream>>>(qb, kb, vtb, ctxb);
    gemm_bt<128, 128, 2, 2, 0, false><<<dim3(8, 32, 2), dim3(256), 0, stream>>>(
        ctxb, 512, 1024, w2 + 3 * wsz, 512, 1024, b2 + 3072, af, 4194304, 1024, 512, 0);
    addnorm_kernel<<<dim3(4096), dim3(256), 0, stream>>>(
        af, af2, h, hb, nra + (l * 3 + 1) * 1024, nrb + (l * 3 + 1) * 1024);

    // ---- ffn ----
    gemm256<1, true><<<dim3(256), dim3(512), 0, stream>>>(
        hb, 1024, wTf1 + (long)l * 4 * wsz, 1024, f1b + (long)l * 4096, midb, 4096, 1024, 0,
        nullptr, nullptr, 16);
    gemm_bt<128, 128, 2, 2, 0, false><<<dim3(8, 32, 2), dim3(256), 0, stream>>>(
        midb, 2048, 4096, wTf2 + (long)l * 4 * wsz, 2048, 4096, f2b + (long)l * 1024, af,
        4194304, 1024, 2048, 0);
    addnorm_kernel<<<dim3(4096), dim3(256), 0, stream>>>(
        af, af2, h, hb, nra + (l * 3 + 2) * 1024, nrb + (l * 3 + 2) * 1024);
  }

  // final projection + log_softmax
  wconv_kernel<<<dim3(1000, 32, 1), dim3(256), 0, stream>>>(fcw, fcT, 1024, 32000);
  if (big) {
    gemm256<1, false><<<dim3(2000), dim3(512), 0, stream>>>(
        hb, 1024, fcT, 1024, fcb, lgb, 32000, 1024, 0, nullptr, nullptr, 16);
    logsoftmax_bf16_kernel<<<dim3(4096), dim3(512), 0, stream>>>(lgb, out);
  } else {
    gemm256<0, false><<<dim3(2000), dim3(512), 0, stream>>>(
        hb, 1024, fcT, 1024, fcb, out, 32000, 1024, 0, nullptr, nullptr, 16);
    logsoftmax_kernel<<<dim3(4096), dim3(256), 0, stream>>>(out);
  }
}

// Round 11
// 3030.511 us; speedup vs baseline: 1.2738x; 1.0188x over previous
//
#include <hip/hip_runtime.h>

typedef __attribute__((ext_vector_type(4))) float f32x4;
typedef __attribute__((ext_vector_type(8))) __bf16 bfx8;
typedef unsigned short u16;
typedef unsigned int u32;

// ---------------- helpers ----------------
__device__ __forceinline__ u16 f2bf(float f) {
  u32 u = __builtin_bit_cast(u32, f);
  u = (u + 0x7FFFu + ((u >> 16) & 1u)) >> 16;
  return (u16)u;
}
__device__ __forceinline__ float bf2f(u16 u) {
  return __builtin_bit_cast(float, ((u32)u) << 16);
}

typedef __attribute__((address_space(1))) const void gvoid;
typedef __attribute__((address_space(3))) void svoid;
__device__ __forceinline__ void gload16(const void* g, void* l) {
  __builtin_amdgcn_global_load_lds((gvoid*)g, (svoid*)l, 16, 0, 0);
}

__device__ __forceinline__ float wredsum(float v) {
#pragma unroll
  for (int o = 32; o; o >>= 1) v += __shfl_xor(v, o, 64);
  return v;
}
__device__ __forceinline__ float wredmax(float v) {
#pragma unroll
  for (int o = 32; o; o >>= 1) v = fmaxf(v, __shfl_xor(v, o, 64));
  return v;
}

// ---------------- small kernels ----------------
// fp32 [z][K][N] -> bf16 [z][N][K]
__global__ __launch_bounds__(256) void wconv_kernel(const float* __restrict__ in,
                                                    u16* __restrict__ out, int K, int N) {
  __shared__ u16 tile[32][33];
  const long z = blockIdx.z;
  const float* iz = in + z * (long)K * N;
  u16* oz = out + z * (long)K * N;
  const int n0 = blockIdx.x << 5, k0 = blockIdx.y << 5;
  const int tx = threadIdx.x & 31, ty = threadIdx.x >> 5;
#pragma unroll
  for (int i = 0; i < 4; ++i)
    tile[ty + 8 * i][tx] = f2bf(iz[(long)(k0 + ty + 8 * i) * N + n0 + tx]);
  __syncthreads();
#pragma unroll
  for (int i = 0; i < 4; ++i)
    oz[(long)(n0 + ty + 8 * i) * K + k0 + tx] = tile[tx][ty + 8 * i];
}

__global__ __launch_bounds__(256) void cvt_kernel(const float* __restrict__ in,
                                                  u16* __restrict__ out, long n) {
  long i = ((long)blockIdx.x * 256 + threadIdx.x) * 4;
  if (i + 3 < n) {
    float4 v = *(const float4*)(in + i);
    ushort4 o = {f2bf(v.x), f2bf(v.y), f2bf(v.z), f2bf(v.w)};
    *(ushort4*)(out + i) = o;
  }
}

__global__ __launch_bounds__(256) void embed_kernel(const int* __restrict__ x,
                                                    const float* __restrict__ emb,
                                                    const float* __restrict__ pe,
                                                    float* __restrict__ h,
                                                    u16* __restrict__ hb) {
  const int row = blockIdx.x;
  const int b = row >> 9, t = row & 511;
  const long tok = (long)x[b * 513 + t];
  const int d = threadIdx.x << 2;
  float4 e = *(const float4*)(emb + tok * 1024 + d);
  float4 p = *(const float4*)(pe + (long)t * 1024 + d);
  float4 v = {e.x + p.x, e.y + p.y, e.z + p.z, e.w + p.w};
  *(float4*)(h + (long)row * 1024 + d) = v;
  ushort4 o = {f2bf(v.x), f2bf(v.y), f2bf(v.z), f2bf(v.w)};
  *(ushort4*)(hb + (long)row * 1024 + d) = o;
}

// h = norm(h + delta + delta2); single-pass dual reduction
__global__ __launch_bounds__(256) void addnorm_kernel(const float* __restrict__ delta,
                                                      const float* __restrict__ delta2,
                                                      float* __restrict__ h,
                                                      u16* __restrict__ hb,
                                                      const float* __restrict__ ga,
                                                      const float* __restrict__ gb) {
  __shared__ float r1[4], r2[4];
  const long row = blockIdx.x;
  const int d = threadIdx.x << 2;
  float4 a = *(const float4*)(h + row * 1024 + d);
  float4 q = *(const float4*)(delta + row * 1024 + d);
  float4 q2 = *(const float4*)(delta2 + row * 1024 + d);
  float x0 = a.x + q.x + q2.x, x1 = a.y + q.y + q2.y;
  float x2 = a.z + q.z + q2.z, x3 = a.w + q.w + q2.w;
  float s1 = wredsum(x0 + x1 + x2 + x3);
  float s2 = wredsum(x0 * x0 + x1 * x1 + x2 * x2 + x3 * x3);
  if ((threadIdx.x & 63) == 0) { r1[threadIdx.x >> 6] = s1; r2[threadIdx.x >> 6] = s2; }
  __syncthreads();
  float S1 = r1[0] + r1[1] + r1[2] + r1[3];
  float S2 = r2[0] + r2[1] + r2[2] + r2[3];
  float mu = S1 * (1.0f / 1024.0f);
  float var = (S2 - S1 * mu) * (1.0f / 1023.0f);
  float inv = 1.0f / (sqrtf(fmaxf(var, 0.f)) + 1e-6f);
  float4 g4 = *(const float4*)(ga + d);
  float4 b4 = *(const float4*)(gb + d);
  float y0 = g4.x * (x0 - mu) * inv + b4.x;
  float y1 = g4.y * (x1 - mu) * inv + b4.y;
  float y2 = g4.z * (x2 - mu) * inv + b4.z;
  float y3 = g4.w * (x3 - mu) * inv + b4.w;
  float4 y = {y0, y1, y2, y3};
  *(float4*)(h + row * 1024 + d) = y;
  ushort4 o = {f2bf(y0), f2bf(y1), f2bf(y2), f2bf(y3)};
  *(ushort4*)(hb + row * 1024 + d) = o;
}

// in-place log_softmax over rows of 32000 fp32 (fallback)
__global__ __launch_bounds__(256) void logsoftmax_kernel(float* __restrict__ lg) {
  const long row = blockIdx.x;
  float* lr = lg + row * 32000L;
  float m = -1e30f, s = 0.f;
  for (int j = threadIdx.x; j < 8000; j += 256) {
    float4 v = *(const float4*)(lr + (long)j * 4);
    float lm = fmaxf(fmaxf(v.x, v.y), fmaxf(v.z, v.w));
    if (lm > m) { s *= __expf(m - lm); m = lm; }
    s += __expf(v.x - m) + __expf(v.y - m) + __expf(v.z - m) + __expf(v.w - m);
  }
#pragma unroll
  for (int o = 32; o; o >>= 1) {
    float om = __shfl_xor(m, o, 64), os = __shfl_xor(s, o, 64);
    float M = fmaxf(m, om);
    s = s * __expf(m - M) + os * __expf(om - M);
    m = M;
  }
  __shared__ float rm[4], rs[4];
  if ((threadIdx.x & 63) == 0) { rm[threadIdx.x >> 6] = m; rs[threadIdx.x >> 6] = s; }
  __syncthreads();
  float M = fmaxf(fmaxf(rm[0], rm[1]), fmaxf(rm[2], rm[3]));
  float S = rs[0] * __expf(rm[0] - M) + rs[1] * __expf(rm[1] - M) +
            rs[2] * __expf(rm[2] - M) + rs[3] * __expf(rm[3] - M);
  float lse = M + __logf(S);
  for (int j = threadIdx.x; j < 8000; j += 256) {
    float4 v = *(const float4*)(lr + (long)j * 4);
    v.x -= lse; v.y -= lse; v.z -= lse; v.w -= lse;
    *(float4*)(lr + (long)j * 4) = v;
  }
}

// LDS-cached log_softmax from bf16 logits -> f32 out.
__global__ __launch_bounds__(512) void logsoftmax_bf16_kernel(const u16* __restrict__ lg,
                                                              float* __restrict__ out) {
  __shared__ u16 rl[32000];
  __shared__ float rr[8];
  const long row = blockIdx.x;
  const u16* lr = lg + row * 32000L;
  float* od = out + row * 32000L;
  const int tid = threadIdx.x;
  float m0 = -1e30f, m1 = -1e30f;
  for (int j = tid * 8; j < 32000; j += 4096) {
    ushort4 a = *(const ushort4*)(lr + j);
    ushort4 b = *(const ushort4*)(lr + j + 4);
    *(ushort4*)&rl[j] = a;
    *(ushort4*)&rl[j + 4] = b;
    m0 = fmaxf(m0, fmaxf(fmaxf(bf2f(a.x), bf2f(a.y)), fmaxf(bf2f(a.z), bf2f(a.w))));
    m1 = fmaxf(m1, fmaxf(fmaxf(bf2f(b.x), bf2f(b.y)), fmaxf(bf2f(b.z), bf2f(b.w))));
  }
  float m = wredmax(fmaxf(m0, m1));
  if ((tid & 63) == 0) rr[tid >> 6] = m;
  __syncthreads();
  m = fmaxf(fmaxf(fmaxf(rr[0], rr[1]), fmaxf(rr[2], rr[3])),
            fmaxf(fmaxf(rr[4], rr[5]), fmaxf(rr[6], rr[7])));
  __syncthreads();
  float s0 = 0.f, s1 = 0.f;
  for (int j = tid * 8; j < 32000; j += 4096) {
    ushort4 a = *(const ushort4*)&rl[j];
    ushort4 b = *(const ushort4*)&rl[j + 4];
    s0 += __expf(bf2f(a.x) - m) + __expf(bf2f(a.y) - m) +
          __expf(bf2f(a.z) - m) + __expf(bf2f(a.w) - m);
    s1 += __expf(bf2f(b.x) - m) + __expf(bf2f(b.y) - m) +
          __expf(bf2f(b.z) - m) + __expf(bf2f(b.w) - m);
  }
  float s = wredsum(s0 + s1);
  if ((tid & 63) == 0) rr[tid >> 6] = s;
  __syncthreads();
  s = rr[0] + rr[1] + rr[2] + rr[3] + rr[4] + rr[5] + rr[6] + rr[7];
  const float lse = m + __logf(s);
  for (int j = tid * 8; j < 32000; j += 4096) {
    ushort4 a = *(const ushort4*)&rl[j];
    ushort4 b = *(const ushort4*)&rl[j + 4];
    float4 o0 = {bf2f(a.x) - lse, bf2f(a.y) - lse, bf2f(a.z) - lse, bf2f(a.w) - lse};
    float4 o1 = {bf2f(b.x) - lse, bf2f(b.y) - lse, bf2f(b.z) - lse, bf2f(b.w) - lse};
    *(float4*)(od + j) = o0;
    *(float4*)(od + j + 4) = o1;
  }
}

// ---------------- fused flash attention (8-wave, LDS-staged, double-buffered) ----------------
template <int SKV>
__global__ __launch_bounds__(512) void attn_kernel(const u16* __restrict__ Q,
                                                   const u16* __restrict__ Kb,
                                                   const u16* __restrict__ Vt,
                                                   u16* __restrict__ ctx) {
  __shared__ u16 Kl[2][4096];    // [buf][64 kv][64 dk], chunk-XOR-swizzled
  __shared__ u16 Vl[2][4096];    // [buf][64 dk][64 kv]
  __shared__ u16 Pl[8][16][72];  // per-wave P: [q][kv]
  const int tid = threadIdx.x, lane = tid & 63, wave = tid >> 6;
  const int l15 = lane & 15, lg = lane >> 4;
  const int bh = blockIdx.y;
  const int qrow = blockIdx.x * 128 + wave * 16 + l15;
  const u16* qp = Q + ((long)bh * 512 + qrow) * 64 + lg * 8;
  bfx8 qf0 = *(const bfx8*)(qp);
  bfx8 qf1 = *(const bfx8*)(qp + 32);

  const int srow = tid >> 3;                  // 0..63
  const int schunk = (tid & 7) ^ (srow & 7);  // pre-swizzled global chunk
  const u16* Kbb = Kb + ((long)bh * SKV + srow) * 64 + schunk * 8;
  const u16* Vtb2 = Vt + ((long)bh * 64 + srow) * SKV + schunk * 8;

  auto stage = [&](int t, int buf) {
    const int kv0 = t * 64;
    gload16(Kbb + (long)kv0 * 64, &Kl[buf][tid * 8]);
    gload16(Vtb2 + kv0, &Vl[buf][tid * 8]);
  };

  const f32x4 zf = {0.f, 0.f, 0.f, 0.f};
  f32x4 acc_o[4] = {zf, zf, zf, zf};
  float mrun = -1e30f, lrun = 0.f;
  const int swk = l15 & 7;
  constexpr int NT = SKV / 64;

  stage(0, 0);
  __syncthreads();
  int buf = 0;
#pragma unroll 1
  for (int t = 0; t < NT; ++t) {
    if (t + 1 < NT) stage(t + 1, buf ^ 1);  // overlaps with compute below
    // S^T tile: lane holds S[q=l15][kv=kvt*16+lg*4+r]
    f32x4 sacc[4];
    __builtin_amdgcn_s_setprio(1);
#pragma unroll
    for (int kvt = 0; kvt < 4; ++kvt) {
      const int krow = kvt * 16 + l15;
      bfx8 kf0 = *(const bfx8*)&Kl[buf][krow * 64 + ((lg ^ swk) << 3)];
      bfx8 kf1 = *(const bfx8*)&Kl[buf][krow * 64 + (((4 + lg) ^ swk) << 3)];
      f32x4 tt = __builtin_amdgcn_mfma_f32_16x16x32_bf16(kf0, qf0, zf, 0, 0, 0);
      sacc[kvt] = __builtin_amdgcn_mfma_f32_16x16x32_bf16(kf1, qf1, tt, 0, 0, 0);
    }
    __builtin_amdgcn_s_setprio(0);
    // online softmax (q = l15; reduce over lg groups)
    float pm = -1e30f;
#pragma unroll
    for (int kvt = 0; kvt < 4; ++kvt)
#pragma unroll
      for (int r = 0; r < 4; ++r) pm = fmaxf(pm, sacc[kvt][r]);
    pm = fmaxf(pm, __shfl_xor(pm, 16, 64));
    pm = fmaxf(pm, __shfl_xor(pm, 32, 64));
    pm *= 0.125f;
    const bool grow = !__all(pm <= mrun);  // exact defer: skip rescale if max unchanged
    const float mnew = grow ? fmaxf(mrun, pm) : mrun;
    float psum = 0.f;
#pragma unroll
    for (int kvt = 0; kvt < 4; ++kvt)
#pragma unroll
      for (int r = 0; r < 4; ++r) {
        float p = __expf(sacc[kvt][r] * 0.125f - mnew);
        psum += p;
        Pl[wave][l15][kvt * 16 + lg * 4 + r] = f2bf(p);
      }
    psum += __shfl_xor(psum, 16, 64);
    psum += __shfl_xor(psum, 32, 64);
    if (grow) {
      const float corr = __expf(mrun - mnew);
      lrun = lrun * corr + psum;
      mrun = mnew;
#pragma unroll
      for (int dt = 0; dt < 4; ++dt) {
        acc_o[dt][0] *= corr; acc_o[dt][1] *= corr;
        acc_o[dt][2] *= corr; acc_o[dt][3] *= corr;
      }
    } else {
      lrun += psum;
    }
    // O^T += V^T-frag x P-frag
    bfx8 pf0 = *(const bfx8*)&Pl[wave][l15][lg * 8];
    bfx8 pf1 = *(const bfx8*)&Pl[wave][l15][32 + lg * 8];
    __builtin_amdgcn_s_setprio(1);
#pragma unroll
    for (int dt = 0; dt < 4; ++dt) {
      const int vrow = dt * 16 + l15;
      bfx8 vf0 = *(const bfx8*)&Vl[buf][vrow * 64 + ((lg ^ swk) << 3)];
      bfx8 vf1 = *(const bfx8*)&Vl[buf][vrow * 64 + (((4 + lg) ^ swk) << 3)];
      acc_o[dt] = __builtin_amdgcn_mfma_f32_16x16x32_bf16(vf0, pf0, acc_o[dt], 0, 0, 0);
      acc_o[dt] = __builtin_amdgcn_mfma_f32_16x16x32_bf16(vf1, pf1, acc_o[dt], 0, 0, 0);
    }
    __builtin_amdgcn_s_setprio(0);
    __syncthreads();  // drains staging vmcnt + ensures buf reads done before overwrite
    buf ^= 1;
  }
  const float inv = 1.0f / lrun;
  const int b = bh >> 4, hh = bh & 15;
  u16* crow = ctx + ((long)b * 512 + qrow) * 1024 + hh * 64;
#pragma unroll
  for (int dt = 0; dt < 4; ++dt)
#pragma unroll
    for (int r = 0; r < 4; ++r)
      crow[dt * 16 + lg * 4 + r] = f2bf(acc_o[dt][r] * inv);
}

// ---------------- 128-class GEMM (2-barrier, m97 structure) ----------------
// z = K-split index; bias only for z==0. EPI: 0=f32 rm, 1=bf16 rm, 3=bf16 [b,h,t,dk]
template <int BM, int BN, int WMW, int WNW, int EPI, bool RELU>
__global__ __launch_bounds__(256) void gemm_bt(const u16* __restrict__ A, long sAz, int lda,
                                               const u16* __restrict__ Bt, long sBz, int ldb,
                                               const float* __restrict__ bias,
                                               void* __restrict__ out, long sCz, int ldc,
                                               int K, int Ttok) {
  constexpr int WROWS = BM / WMW, WCOLS = BN / WNW;
  constexpr int MI = WROWS / 16, NI = WCOLS / 16;
  __shared__ u16 As[BM * 32];
  __shared__ u16 Bs[BN * 32];
  const int tid = threadIdx.x, lane = tid & 63, wave = tid >> 6;
  const int l15 = lane & 15, lg = lane >> 4;
  const int wm = wave / WNW, wn = wave % WNW;
  const int bx = blockIdx.x, by = blockIdx.y;
  const long z = blockIdx.z;
  const int srow = tid >> 2, scol = (tid & 3) << 3;
  const u16* Aa = A + z * sAz + (long)(by * BM + srow) * lda + scol;
  const u16* Ba = Bt + z * sBz + (long)(bx * BN + srow) * ldb + scol;

  f32x4 acc[MI][NI];
#pragma unroll
  for (int i = 0; i < MI; ++i)
#pragma unroll
    for (int j = 0; j < NI; ++j) acc[i][j] = (f32x4){0.f, 0.f, 0.f, 0.f};

  for (int kt = 0; kt < K; kt += 32) {
#pragma unroll
    for (int i = 0; i < BM / 64; ++i)
      gload16(Aa + (long)i * 64 * lda + kt, &As[i * 2048 + tid * 8]);
#pragma unroll
    for (int i = 0; i < BN / 64; ++i)
      gload16(Ba + (long)i * 64 * ldb + kt, &Bs[i * 2048 + tid * 8]);
    __syncthreads();
    bfx8 afr[MI], bfr[NI];
#pragma unroll
    for (int i = 0; i < MI; ++i)
      afr[i] = *(const bfx8*)&As[(wm * WROWS + i * 16 + l15) * 32 + (lg << 3)];
#pragma unroll
    for (int j = 0; j < NI; ++j)
      bfr[j] = *(const bfx8*)&Bs[(wn * WCOLS + j * 16 + l15) * 32 + (lg << 3)];
#pragma unroll
    for (int i = 0; i < MI; ++i)
#pragma unroll
      for (int j = 0; j < NI; ++j)
        acc[i][j] = __builtin_amdgcn_mfma_f32_16x16x32_bf16(afr[i], bfr[j], acc[i][j], 0, 0, 0);
    __syncthreads();
  }

  const int gm0 = by * BM + wm * WROWS;
  const int gn0 = bx * BN + wn * WCOLS;
#pragma unroll
  for (int i = 0; i < MI; ++i) {
#pragma unroll
    for (int j = 0; j < NI; ++j) {
      const int gn = gn0 + j * 16 + l15;
      const float bv = (bias && z == 0) ? bias[gn] : 0.f;
#pragma unroll
      for (int r = 0; r < 4; ++r) {
        const int gm = gm0 + i * 16 + (lg << 2) + r;
        float v = acc[i][j][r] + bv;
        if (RELU) v = fmaxf(v, 0.f);
        if constexpr (EPI == 0) {
          ((float*)out)[z * sCz + (long)gm * ldc + gn] = v;
        } else if constexpr (EPI == 1) {
          ((u16*)out)[z * sCz + (long)gm * ldc + gn] = f2bf(v);
        } else if constexpr (EPI == 3) {
          const int b = gm / Ttok, t = gm - b * Ttok;
          const int hh = gn >> 6, dk = gn & 63;
          ((u16*)out)[(((long)(b * 16 + hh) * Ttok + t) << 6) + dk] = f2bf(v);
        }
      }
    }
  }
}

// ---------------- 256x256 8-phase GEMM (T2+T3+T4+T5) ----------------
// L2-aware XCD chunking: per XCD S=gx/8 mt-rows x full nt sweep.
// BMAP=1: cross-KV batched mapping — B rows / bias gathered from [L][4][1024][.]
// weight stack (sections never straddled: 256-row tiles, 1024-row sections).
// EPI: 0=f32 rm, 1=bf16 rm, 6=self-QKV fused, 7=cross-KV fused (per-layer),
//      8=batched cross-KV (out=kb6 [6][B,H,1024,64], out2=vtb6 [6][B,H,64,1024])
#define MMAQ(hm, hn)                                                                   \
  {                                                                                    \
    _Pragma("unroll") for (int kk = 0; kk < 2; ++kk)                                   \
        _Pragma("unroll") for (int i = 0; i < 4; ++i)                                  \
            _Pragma("unroll") for (int jn = 0; jn < 2; ++jn)                           \
                acc[(hm)*4 + i][(hn)*2 + jn] = __builtin_amdgcn_mfma_f32_16x16x32_bf16( \
                    a[i][kk], b[jn][kk], acc[(hm)*4 + i][(hn)*2 + jn], 0, 0, 0);       \
  }

template <int EPI, bool RELU, int BMAP>
__global__ __launch_bounds__(512, 2) void gemm256(const u16* __restrict__ A, int lda,
                                                  const u16* __restrict__ Bt, int ldb,
                                                  const float* __restrict__ bias,
                                                  void* __restrict__ out, int ldc, int K,
                                                  int Ttok, void* __restrict__ out2,
                                                  void* __restrict__ out3, int gx) {
  __shared__ u16 lds[2][2][2][8192];  // [dbuf][A/B][half][128*64]
  const int tid = threadIdx.x, lane = tid & 63;
  const int wid = tid >> 6, wm = wid >> 2, wn = wid & 3;
  const int l15 = lane & 15, lg = lane >> 4;
  const int S = gx >> 3;  // mt-rows per XCD (gx % 8 == 0)
  const int xcd = blockIdx.x & 7, idx = blockIdx.x >> 3;
  const int mt = xcd * S + idx % S;
  const int nt_ = idx / S;
  const int NT = K >> 6;

  const int r0 = tid >> 3;
  const int blkx = (tid & 7) ^ (r0 & 7);
  const int n0 = nt_ * 256;
  long brow0;
  if constexpr (BMAP == 1)
    brow0 = (long)(n0 >> 11) * 4096 + 1024 + (n0 & 2047);  // skip q-section per layer
  else
    brow0 = n0;
  const u16* Abase = A + (long)(mt * 256 + r0) * lda + blkx * 8;
  const u16* Bbase = Bt + (brow0 + r0) * ldb + blkx * 8;

  auto stageA = [&](int s, int half) {
    const int kts = (s < NT ? s : NT - 1) << 6;
    const u16* g = Abase + (long)(half * 128) * lda + kts;
    gload16(g, &lds[s & 1][0][half][tid * 8]);
    gload16(g + (long)64 * lda, &lds[s & 1][0][half][(512 + tid) * 8]);
  };
  auto stageB = [&](int s, int half) {
    const int kts = (s < NT ? s : NT - 1) << 6;
    const u16* g = Bbase + (long)(half * 128) * ldb + kts;
    gload16(g, &lds[s & 1][1][half][tid * 8]);
    gload16(g + (long)64 * ldb, &lds[s & 1][1][half][(512 + tid) * 8]);
  };

  f32x4 acc[8][4];
#pragma unroll
  for (int i = 0; i < 8; ++i)
#pragma unroll
    for (int j = 0; j < 4; ++j) acc[i][j] = (f32x4){0.f, 0.f, 0.f, 0.f};
  bfx8 a[4][2], b[2][2];

  const int sw = l15 & 7;
  auto loadA = [&](int buf, int hm) {
#pragma unroll
    for (int i = 0; i < 4; ++i) {
      const int row = hm * 64 + i * 16 + l15;
#pragma unroll
      for (int kk = 0; kk < 2; ++kk)
        a[i][kk] = *(const bfx8*)&lds[buf][0][wm][row * 64 + (((kk * 4 + lg) ^ sw) << 3)];
    }
  };
  auto loadB = [&](int buf, int hn) {
#pragma unroll
    for (int jn = 0; jn < 2; ++jn) {
      const int row = (wn & 1) * 64 + hn * 32 + jn * 16 + l15;
#pragma unroll
      for (int kk = 0; kk < 2; ++kk)
        b[jn][kk] = *(const bfx8*)&lds[buf][1][wn >> 1][row * 64 + (((kk * 4 + lg) ^ sw) << 3)];
    }
  };

  stageA(0, 0); stageA(0, 1); stageB(0, 0); stageB(0, 1);
  stageA(1, 0); stageA(1, 1);
  asm volatile("s_waitcnt vmcnt(4)" ::: "memory");
  __builtin_amdgcn_s_barrier();

  for (int t = 0; t < NT; ++t) {
    const int p = t & 1;
    loadA(p, 0); loadB(p, 0);
    stageB(t + 1, 0);
    __builtin_amdgcn_s_barrier();
    asm volatile("s_waitcnt lgkmcnt(0)" ::: "memory");
    __builtin_amdgcn_s_setprio(1);
    MMAQ(0, 0);
    __builtin_amdgcn_s_setprio(0);
    __builtin_amdgcn_s_barrier();
    loadB(p, 1);
    stageB(t + 1, 1);
    __builtin_amdgcn_s_barrier();
    asm volatile("s_waitcnt lgkmcnt(0)" ::: "memory");
    __builtin_amdgcn_s_setprio(1);
    MMAQ(0, 1);
    __builtin_amdgcn_s_setprio(0);
    __builtin_amdgcn_s_barrier();
    loadA(p, 1); loadB(p, 0);
    stageA(t + 2, 0);
    __builtin_amdgcn_s_barrier();
    asm volatile("s_waitcnt lgkmcnt(0)" ::: "memory");
    __builtin_amdgcn_s_setprio(1);
    MMAQ(1, 0);
    __builtin_amdgcn_s_setprio(0);
    __builtin_amdgcn_s_barrier();
    loadB(p, 1);
    stageA(t + 2, 1);
    asm volatile("s_waitcnt vmcnt(4)" ::: "memory");
    __builtin_amdgcn_s_barrier();
    asm volatile("s_waitcnt lgkmcnt(0)" ::: "memory");
    __builtin_amdgcn_s_setprio(1);
    MMAQ(1, 1);
    __builtin_amdgcn_s_setprio(0);
    __builtin_amdgcn_s_barrier();
  }

  const int gm0 = mt * 256 + wm * 128;
  const int gn0 = nt_ * 256 + wn * 64;
#pragma unroll
  for (int ii = 0; ii < 8; ++ii) {
#pragma unroll
    for (int jj = 0; jj < 4; ++jj) {
      const int gn = gn0 + jj * 16 + l15;
      float bv;
      if constexpr (BMAP == 1)
        bv = bias[(gn >> 11) * 4096 + 1024 + (gn & 2047)];
      else
        bv = bias ? bias[gn] : 0.f;
#pragma unroll
      for (int r = 0; r < 4; ++r) {
        const int gm = gm0 + ii * 16 + (lg << 2) + r;
        float v = acc[ii][jj][r] + bv;
        if (RELU) v = fmaxf(v, 0.f);
        if constexpr (EPI == 0) {
          ((float*)out)[(long)gm * ldc + gn] = v;
        } else if constexpr (EPI == 1) {
          ((u16*)out)[(long)gm * ldc + gn] = f2bf(v);
        } else if constexpr (EPI == 6) {
          const int bq = gm / Ttok, t2 = gm - bq * Ttok;
          const int sec = gn >> 10, w1 = gn & 1023;
          const int hh = w1 >> 6, dk = w1 & 63;
          const u16 val = f2bf(v);
          if (sec == 0)
            ((u16*)out)[(((long)(bq * 16 + hh) * Ttok + t2) << 6) + dk] = val;
          else if (sec == 1)
            ((u16*)out2)[(((long)(bq * 16 + hh) * Ttok + t2) << 6) + dk] = val;
          else
            ((u16*)out3)[((long)((bq * 16 + hh) << 6) + dk) * Ttok + t2] = val;
        } else if constexpr (EPI == 7) {
          const int bq = gm / Ttok, t2 = gm - bq * Ttok;
          const int sec = gn >> 10, w1 = gn & 1023;
          const int hh = w1 >> 6, dk = w1 & 63;
          const u16 val = f2bf(v);
          if (sec == 0)
            ((u16*)out)[(((long)(bq * 16 + hh) * Ttok + t2) << 6) + dk] = val;
          else
            ((u16*)out2)[((long)((bq * 16 + hh) << 6) + dk) * Ttok + t2] = val;
        } else if constexpr (EPI == 8) {
          const int l = gn >> 11, inner = gn & 2047;
          const int sec = inner >> 10, w1 = inner & 1023;
          const int hh = w1 >> 6, dk = w1 & 63;
          const int bq = gm >> 10, t2 = gm & 1023;  // encoder S=1024
          const u16 val = f2bf(v);
          if (sec == 0)
            ((u16*)out)[((((long)l * 8 + bq) * 16 + hh) * 1024 + t2) * 64 + dk] = val;
          else
            ((u16*)out2)[((((long)l * 8 + bq) * 16 + hh) * 64 + dk) * 1024 + t2] = val;
        }
      }
    }
  }
}

// ---------------- driver ----------------
extern "C" void kernel_launch(void* const* d_in, const int* in_sizes, int n_in,
                              void* d_out, int out_size, void* d_ws, size_t ws_size,
                              hipStream_t stream) {
  const int* x = (const int*)d_in[0];
  const float* enc = (const float*)d_in[1];
  const float* emb = (const float*)d_in[2];
  const float* pe = (const float*)d_in[3];
  const float* a1w = (const float*)d_in[4];
  const float* a1b = (const float*)d_in[5];
  const float* a2w = (const float*)d_in[6];
  const float* a2b = (const float*)d_in[7];
  const float* nra = (const float*)d_in[8];
  const float* nrb = (const float*)d_in[9];
  const float* f1w = (const float*)d_in[10];
  const float* f1b = (const float*)d_in[11];
  const float* f2w = (const float*)d_in[12];
  const float* f2b = (const float*)d_in[13];
  const float* fcw = (const float*)d_in[14];
  const float* fcb = (const float*)d_in[15];
  float* out = (float*)d_out;

  char* base = (char*)d_ws;
  size_t off = 0;
  auto alloc = [&](size_t bytes) -> void* {
    void* p = base + off;
    off += (bytes + 255) & ~(size_t)255;
    return p;
  };
  const long wsz = 1024 * 1024;
  const bool big = ws_size >= (600ull << 20);
  u16* wT = (u16*)alloc(96ull * wsz * 2);    // all transposed weights: a1|a2|f1|f2
  u16* encb = (u16*)alloc(8ull * wsz * 2);   // encoder bf16 [8192,1024]
  float* h = (float*)alloc(4ull * wsz * 4);  // residual f32 [4096,1024]
  u16* hb = (u16*)alloc(4ull * wsz * 2);     // bf16 copy of h
  u16* qb = (u16*)alloc(4ull * wsz * 2);     // [B,H,512,64]
  u16* kb = (u16*)alloc(8ull * wsz * 2);     // self/per-layer K [B,H,<=1024,64]
  u16* vtb = (u16*)alloc(8ull * wsz * 2);    // self/per-layer V^T [B,H,64,<=1024]
  u16* ctxb = (u16*)alloc(4ull * wsz * 2);   // [4096,1024] bf16
  float* af = (float*)alloc(4ull * wsz * 4); // K-split partial 0
  float* af2 = (float*)alloc(4ull * wsz * 4);// K-split partial 1
  u16* midb = (u16*)alloc(16ull * wsz * 2);  // FFN mid bf16 [4096,4096]
  u16* fcT = qb;                             // fc^T (64 MB) aliases qb.. after layers
  // kv6 region (201 MB, layers) time-shares with bf16 logits (250 MB, fc epilogue)
  u16* kv6 = big ? (u16*)alloc(262144000) : nullptr;
  u16* kb6 = kv6;                            // [6][B,H,1024,64]
  u16* vtb6 = kv6 ? kv6 + 50331648 : nullptr;// [6][B,H,64,1024]
  u16* lgb = kv6;                            // bf16 logits [4096,32000]

  u16* wTa1 = wT;               // [L][4][1024][1024]^T
  u16* wTa2 = wT + 24 * wsz;
  u16* wTf1 = wT + 48 * wsz;    // [L][4096][1024]
  u16* wTf2 = wT + 72 * wsz;    // [L][1024][4096]

  cvt_kernel<<<dim3(8192), dim3(256), 0, stream>>>(enc, encb, 8ll * wsz);
  embed_kernel<<<dim3(4096), dim3(256), 0, stream>>>(x, emb, pe, h, hb);
  wconv_kernel<<<dim3(32, 32, 24), dim3(256), 0, stream>>>(a1w, wTa1, 1024, 1024);
  wconv_kernel<<<dim3(32, 32, 24), dim3(256), 0, stream>>>(a2w, wTa2, 1024, 1024);
  wconv_kernel<<<dim3(128, 32, 6), dim3(256), 0, stream>>>(f1w, wTf1, 1024, 4096);
  wconv_kernel<<<dim3(32, 128, 6), dim3(256), 0, stream>>>(f2w, wTf2, 4096, 1024);

  // batched cross-attention K/V for ALL layers (encoder-only dependence):
  // M=8192, N=6*2048, K=1024; B rows/bias gathered from wTa2/a2b via BMAP.
  if (big) {
    gemm256<8, false, 1><<<dim3(1536), dim3(512), 0, stream>>>(
        encb, 1024, wTa2, 1024, a2b, kb6, 0, 1024, 1024, vtb6, nullptr, 32);
  }

  for (int l = 0; l < 6; ++l) {
    const float* b1 = a1b + (long)l * 4096;
    const float* b2 = a2b + (long)l * 4096;
    const u16* w1 = wTa1 + (long)l * 4 * wsz;
    const u16* w2 = wTa2 + (long)l * 4 * wsz;

    // ---- self attention ----
    gemm256<6, false, 0><<<dim3(192), dim3(512), 0, stream>>>(
        hb, 1024, w1, 1024, b1, qb, 0, 1024, 512, kb, vtb, 16);
    attn_kernel<512><<<dim3(4, 128), dim3(512), 0, stream>>>(qb, kb, vtb, ctxb);
    gemm_bt<128, 128, 2, 2, 0, false><<<dim3(8, 32, 2), dim3(256), 0, stream>>>(
        ctxb, 512, 1024, w1 + 3 * wsz, 512, 1024, b1 + 3072, af, 4194304, 1024, 512, 0);
    addnorm_kernel<<<dim3(4096), dim3(256), 0, stream>>>(
        af, af2, h, hb, nra + (l * 3 + 0) * 1024, nrb + (l * 3 + 0) * 1024);

    // ---- cross attention ----
    gemm_bt<64, 128, 2, 2, 3, false><<<dim3(8, 64, 1), dim3(256), 0, stream>>>(
        hb, 0, 1024, w2, 0, 1024, b2, qb, 0, 0, 1024, 512);
    const u16* lK;
    const u16* lV;
    if (big) {
      lK = kb6 + (long)l * 8388608;
      lV = vtb6 + (long)l * 8388608;
    } else {
      gemm256<7, false, 0><<<dim3(256), dim3(512), 0, stream>>>(
          encb, 1024, w2 + wsz, 1024, b2 + 1024, kb, 0, 1024, 1024, vtb, nullptr, 32);
      lK = kb;
      lV = vtb;
    }
    attn_kernel<1024><<<dim3(4, 128), dim3(512), 0, stream>>>(qb, lK, lV, ctxb);
    gemm_bt<128, 128, 2, 2, 0, false><<<dim3(8, 32, 2), dim3(256), 0, stream>>>(
        ctxb, 512, 1024, w2 + 3 * wsz, 512, 1024, b2 + 3072, af, 4194304, 1024, 512, 0);
    addnorm_kernel<<<dim3(4096), dim3(256), 0, stream>>>(
        af, af2, h, hb, nra + (l * 3 + 1) * 1024, nrb + (l * 3 + 1) * 1024);

    // ---- ffn ----
    gemm256<1, true, 0><<<dim3(256), dim3(512), 0, stream>>>(
        hb, 1024, wTf1 + (long)l * 4 * wsz, 1024, f1b + (long)l * 4096, midb, 4096, 1024, 0,
        nullptr, nullptr, 16);
    gemm_bt<128, 128, 2, 2, 0, false><<<dim3(8, 32, 2), dim3(256), 0, stream>>>(
        midb, 2048, 4096, wTf2 + (long)l * 4 * wsz, 2048, 4096, f2b + (long)l * 1024, af,
        4194304, 1024, 2048, 0);
    addnorm_kernel<<<dim3(4096), dim3(256), 0, stream>>>(
        af, af2, h, hb, nra + (l * 3 + 2) * 1024, nrb + (l * 3 + 2) * 1024);
  }

  // final projection + log_softmax
  wconv_kernel<<<dim3(1000, 32, 1), dim3(256), 0, stream>>>(fcw, fcT, 1024, 32000);
  if (big) {
    gemm256<1, false, 0><<<dim3(2000), dim3(512), 0, stream>>>(
        hb, 1024, fcT, 1024, fcb, lgb, 32000, 1024, 0, nullptr, nullptr, 16);
    logsoftmax_bf16_kernel<<<dim3(4096), dim3(512), 0, stream>>>(lgb, out);
  } else {
    gemm256<0, false, 0><<<dim3(2000), dim3(512), 0, stream>>>(
        hb, 1024, fcT, 1024, fcb, out, 32000, 1024, 0, nullptr, nullptr, 16);
    logsoftmax_kernel<<<dim3(4096), dim3(256), 0, stream>>>(out);
  }
}